// Round 2
// baseline (355.910 us; speedup 1.0000x reference)
//
#include <hip/hip_runtime.h>
#include <math.h>

#define D 256
#define H2 512
#define HEADS 8
#define DH 32
#define L 25
#define GH 64
#define GW 64
#define NN 4096
#define NB 8          // nodes per block
#define PAD 12        // LDS row stride in floats: 48B -> rows 16B-aligned
#define EPS 1e-5f
#define SCALE 0.17677669529663687f  // 1/sqrt(32)

__device__ __forceinline__ bool act_at(const int* __restrict__ active, int h, int w) {
    if (h < 0 || h >= GH || w < 0 || w >= GW) return false;
    if (h == 2 && w == 2) return false;   // ap.at[:, center, center].set(False) quirk
    return active[h * GW + w] != 0;
}

__device__ __forceinline__ void ld8(const float* __restrict__ row, float* s) {
    float4 a = *(const float4*)row;
    float4 b = *(const float4*)(row + 4);
    s[0] = a.x; s[1] = a.y; s[2] = a.z; s[3] = a.w;
    s[4] = b.x; s[5] = b.y; s[6] = b.z; s[7] = b.w;
}

// ---------------- Kernel A: batched projections ----------------
__global__ __launch_bounds__(256)
void proj_kernel(const float* __restrict__ x,
                 const float* __restrict__ mem,
                 const int* __restrict__ active,
                 const float* __restrict__ attn_w,
                 const float* __restrict__ attn_b,
                 const float* __restrict__ pattn_w,
                 const float* __restrict__ pattn_b,
                 float* __restrict__ Q1, float* __restrict__ K1, float* __restrict__ V1,
                 float* __restrict__ K2, float* __restrict__ V2) {
    const int n0 = blockIdx.x * NB;
    const int j = threadIdx.x;
    __shared__ float xT[D][PAD];
    __shared__ float mT[D][PAD];
    #pragma unroll
    for (int m = 0; m < NB; ++m) {
        int n = n0 + m;
        bool a = act_at(active, n / GW, n % GW);
        xT[j][m] = a ? x[(size_t)n * D + j] : 0.0f;
        mT[j][m] = mem[(size_t)n * D + j];
    }
    __syncthreads();

    const float* Wq  = attn_w;
    const float* Wk  = attn_w + D * D;
    const float* Wv  = attn_w + 2 * D * D;
    const float* Wk2 = pattn_w + D * D;
    const float* Wv2 = pattn_w + 2 * D * D;

    float aq[NB], ak[NB], av[NB];
    {
        float bq = attn_b[j], bk = attn_b[D + j], bv = attn_b[2 * D + j];
        #pragma unroll
        for (int m = 0; m < NB; ++m) { aq[m] = bq; ak[m] = bk; av[m] = bv; }
    }
    #pragma unroll 4
    for (int i = 0; i < D; ++i) {
        float s[NB];
        ld8(&xT[i][0], s);
        float wq = Wq[i * D + j], wk = Wk[i * D + j], wv = Wv[i * D + j];
        #pragma unroll
        for (int m = 0; m < NB; ++m) {
            aq[m] = fmaf(s[m], wq, aq[m]);
            ak[m] = fmaf(s[m], wk, ak[m]);
            av[m] = fmaf(s[m], wv, av[m]);
        }
    }
    #pragma unroll
    for (int m = 0; m < NB; ++m) {
        Q1[(size_t)(n0 + m) * D + j] = aq[m];
        K1[(size_t)(n0 + m) * D + j] = ak[m];
        V1[(size_t)(n0 + m) * D + j] = av[m];
    }

    float k2[NB], v2[NB];
    {
        float bk = pattn_b[D + j], bv = pattn_b[2 * D + j];
        #pragma unroll
        for (int m = 0; m < NB; ++m) { k2[m] = bk; v2[m] = bv; }
    }
    #pragma unroll 4
    for (int i = 0; i < D; ++i) {
        float s[NB];
        ld8(&mT[i][0], s);
        float wk = Wk2[i * D + j], wv = Wv2[i * D + j];
        #pragma unroll
        for (int m = 0; m < NB; ++m) {
            k2[m] = fmaf(s[m], wk, k2[m]);
            v2[m] = fmaf(s[m], wv, v2[m]);
        }
    }
    #pragma unroll
    for (int m = 0; m < NB; ++m) {
        K2[(size_t)(n0 + m) * D + j] = k2[m];
        V2[(size_t)(n0 + m) * D + j] = v2[m];
    }
}

// ---------------- batched 8-row layernorm ----------------
// v[m] holds this thread's (col j) value for node m. Normalizes in place.
__device__ __forceinline__ void ln8(float* v, const float* __restrict__ g,
                                    const float* __restrict__ b,
                                    float (*red)[12], int j, int lane, int wid) {
    float gg = g[j], bb = b[j];
    #pragma unroll
    for (int m = 0; m < NB; ++m) {
        float s1 = v[m], s2 = v[m] * v[m];
        #pragma unroll
        for (int off = 32; off > 0; off >>= 1) {
            s1 += __shfl_down(s1, off);
            s2 += __shfl_down(s2, off);
        }
        if (lane == 0) { red[m][wid] = s1; red[m][4 + wid] = s2; }
    }
    __syncthreads();
    if (j < NB) {
        float s1 = red[j][0] + red[j][1] + red[j][2] + red[j][3];
        float s2 = red[j][4] + red[j][5] + red[j][6] + red[j][7];
        float mu = s1 * (1.0f / D);
        float var = s2 * (1.0f / D) - mu * mu;
        red[j][8] = mu;
        red[j][9] = rsqrtf(var + EPS);
    }
    __syncthreads();
    #pragma unroll
    for (int m = 0; m < NB; ++m)
        v[m] = (v[m] - red[m][8]) * red[m][9] * gg + bb;
    __syncthreads();   // protect red[] for the next call
}

// ---------------- Kernel B: batched attention + FF ----------------
__global__ __launch_bounds__(256)
void attn_kernel(const float* __restrict__ x,
                 const int* __restrict__ active,
                 const float* __restrict__ attn_w,  const float* __restrict__ attn_b,
                 const float* __restrict__ pattn_w, const float* __restrict__ pattn_b,
                 const float* __restrict__ ff_w1,   const float* __restrict__ ff_b1,
                 const float* __restrict__ ff_w2,   const float* __restrict__ ff_b2,
                 const float* __restrict__ ln_g,    const float* __restrict__ ln_b,
                 const float* __restrict__ Q1, const float* __restrict__ K1,
                 const float* __restrict__ V1, const float* __restrict__ K2,
                 const float* __restrict__ V2,
                 float* __restrict__ out) {
    const int n0 = blockIdx.x * NB;
    const int j = threadIdx.x;
    const int lane = j & 63, wid = j >> 6;
    const int hd_of_j = j >> 5;   // head owning column j

    __shared__ float sT[D][PAD];          // state, transposed
    __shared__ float tT[D][PAD];          // scratch (q-proj / attention out)
    __shared__ float hT[H2][PAD];         // FF hidden, transposed
    __shared__ float sc[NB][HEADS][L + 1];
    __shared__ float red[NB][12];
    __shared__ int   nbIdx[NB][L];
    __shared__ unsigned char val1[NB][L];
    __shared__ int actC[NB];

    if (j < NB * L) {
        int m = j / L, l = j - m * L;
        int n = n0 + m, h = n / GW, w = n % GW;
        int hh = h + l / 5 - 2, ww = w + l % 5 - 2;
        bool ib = (hh >= 0 && hh < GH && ww >= 0 && ww < GW);
        nbIdx[m][l] = ib ? hh * GW + ww : -1;
        val1[m][l] = act_at(active, hh, ww) ? 1 : 0;
    }
    if (j < NB) {
        int n = n0 + j;
        actC[j] = act_at(active, n / GW, n % GW) ? 1 : 0;
    }
    __syncthreads();

    // ---- MHA1 scores (masked) ----
    for (int t = j; t < NB * HEADS * L; t += 256) {
        int m = t / (HEADS * L);
        int r = t - m * HEADS * L;
        int hd = r / L, l = r - hd * L;
        float s = -1e30f;
        if (val1[m][l]) {
            const float4* q = (const float4*)(Q1 + (size_t)(n0 + m) * D + hd * DH);
            const float4* k = (const float4*)(K1 + (size_t)nbIdx[m][l] * D + hd * DH);
            float acc = 0.0f;
            #pragma unroll
            for (int d = 0; d < DH / 4; ++d) {
                float4 qa = q[d], ka = k[d];
                acc = fmaf(qa.x, ka.x, acc); acc = fmaf(qa.y, ka.y, acc);
                acc = fmaf(qa.z, ka.z, acc); acc = fmaf(qa.w, ka.w, acc);
            }
            s = acc * SCALE;
        }
        sc[m][hd][l] = s;
    }
    __syncthreads();
    if (j < NB * HEADS) {
        int m = j / HEADS, hd = j - m * HEADS;
        float mx = -1e30f;
        for (int l = 0; l < L; ++l) mx = fmaxf(mx, sc[m][hd][l]);
        float e[L], sum = 0.0f;
        for (int l = 0; l < L; ++l) { e[l] = expf(sc[m][hd][l] - mx); sum += e[l]; }
        float inv = 1.0f / sum;
        for (int l = 0; l < L; ++l) sc[m][hd][l] = e[l] * inv;
    }
    __syncthreads();
    // ---- MHA1 PV -> tT ----
    {
        float o[NB];
        #pragma unroll
        for (int m = 0; m < NB; ++m) o[m] = 0.0f;
        for (int m = 0; m < NB; ++m)
            for (int l = 0; l < L; ++l)
                if (val1[m][l])
                    o[m] = fmaf(sc[m][hd_of_j][l], V1[(size_t)nbIdx[m][l] * D + j], o[m]);
        #pragma unroll
        for (int m = 0; m < NB; ++m) tT[j][m] = o[m];
    }
    __syncthreads();

    // ---- Wo1 matvec + residual + LN0 ----
    float sreg[NB];
    {
        const float* Wo1 = attn_w + 3 * D * D;
        float acc[NB];
        float bo = attn_b[3 * D + j];
        #pragma unroll
        for (int m = 0; m < NB; ++m) acc[m] = bo;
        #pragma unroll 4
        for (int i = 0; i < D; ++i) {
            float s[NB];
            ld8(&tT[i][0], s);
            float wv = Wo1[i * D + j];
            #pragma unroll
            for (int m = 0; m < NB; ++m) acc[m] = fmaf(s[m], wv, acc[m]);
        }
        #pragma unroll
        for (int m = 0; m < NB; ++m) acc[m] += x[(size_t)(n0 + m) * D + j];
        ln8(acc, ln_g, ln_b, red, j, lane, wid);
        #pragma unroll
        for (int m = 0; m < NB; ++m) { sreg[m] = acc[m]; sT[j][m] = acc[m]; }
    }
    __syncthreads();

    // ---- MHA2 q-proj -> tT ----
    {
        const float* Wq2 = pattn_w;
        float acc[NB];
        float bq = pattn_b[j];
        #pragma unroll
        for (int m = 0; m < NB; ++m) acc[m] = bq;
        #pragma unroll 4
        for (int i = 0; i < D; ++i) {
            float s[NB];
            ld8(&sT[i][0], s);
            float wv = Wq2[i * D + j];
            #pragma unroll
            for (int m = 0; m < NB; ++m) acc[m] = fmaf(s[m], wv, acc[m]);
        }
        #pragma unroll
        for (int m = 0; m < NB; ++m) tT[j][m] = acc[m];
    }
    __syncthreads();
    // ---- MHA2 scores (no mask; OOB -> bias-only K) ----
    for (int t = j; t < NB * HEADS * L; t += 256) {
        int m = t / (HEADS * L);
        int r = t - m * HEADS * L;
        int hd = r / L, l = r - hd * L;
        int nb = nbIdx[m][l];
        const float* kr = (nb >= 0) ? (K2 + (size_t)nb * D + hd * DH)
                                    : (pattn_b + D + hd * DH);
        float acc = 0.0f;
        #pragma unroll
        for (int d = 0; d < DH; ++d)
            acc = fmaf(tT[hd * DH + d][m], kr[d], acc);
        sc[m][hd][l] = acc * SCALE;
    }
    __syncthreads();
    if (j < NB * HEADS) {
        int m = j / HEADS, hd = j - m * HEADS;
        float mx = -1e30f;
        for (int l = 0; l < L; ++l) mx = fmaxf(mx, sc[m][hd][l]);
        float e[L], sum = 0.0f;
        for (int l = 0; l < L; ++l) { e[l] = expf(sc[m][hd][l] - mx); sum += e[l]; }
        float inv = 1.0f / sum;
        for (int l = 0; l < L; ++l) sc[m][hd][l] = e[l] * inv;
    }
    __syncthreads();
    // ---- MHA2 PV -> tT ----
    {
        float o[NB];
        #pragma unroll
        for (int m = 0; m < NB; ++m) o[m] = 0.0f;
        float bvv = pattn_b[2 * D + j];
        for (int m = 0; m < NB; ++m)
            for (int l = 0; l < L; ++l) {
                int nb = nbIdx[m][l];
                float vv = (nb >= 0) ? V2[(size_t)nb * D + j] : bvv;
                o[m] = fmaf(sc[m][hd_of_j][l], vv, o[m]);
            }
        #pragma unroll
        for (int m = 0; m < NB; ++m) tT[j][m] = o[m];
    }
    __syncthreads();

    // ---- Wo2 matvec + residual + LN2 ----
    {
        const float* Wo2 = pattn_w + 3 * D * D;
        float acc[NB];
        float bo = pattn_b[3 * D + j];
        #pragma unroll
        for (int m = 0; m < NB; ++m) acc[m] = bo;
        #pragma unroll 4
        for (int i = 0; i < D; ++i) {
            float s[NB];
            ld8(&tT[i][0], s);
            float wv = Wo2[i * D + j];
            #pragma unroll
            for (int m = 0; m < NB; ++m) acc[m] = fmaf(s[m], wv, acc[m]);
        }
        #pragma unroll
        for (int m = 0; m < NB; ++m) acc[m] += sreg[m];
        ln8(acc, ln_g + 2 * D, ln_b + 2 * D, red, j, lane, wid);
        #pragma unroll
        for (int m = 0; m < NB; ++m) { sreg[m] = acc[m]; sT[j][m] = acc[m]; }
    }
    __syncthreads();

    // ---- FF1: hidden cols j and j+256 ----
    {
        float a0[NB], a1[NB];
        float b0 = ff_b1[j], b1 = ff_b1[j + D];
        #pragma unroll
        for (int m = 0; m < NB; ++m) { a0[m] = b0; a1[m] = b1; }
        #pragma unroll 4
        for (int i = 0; i < D; ++i) {
            float s[NB];
            ld8(&sT[i][0], s);
            float w0 = ff_w1[(size_t)i * H2 + j];
            float w1 = ff_w1[(size_t)i * H2 + j + D];
            #pragma unroll
            for (int m = 0; m < NB; ++m) {
                a0[m] = fmaf(s[m], w0, a0[m]);
                a1[m] = fmaf(s[m], w1, a1[m]);
            }
        }
        #pragma unroll
        for (int m = 0; m < NB; ++m) {
            hT[j][m]     = fmaxf(a0[m], 0.0f);
            hT[j + D][m] = fmaxf(a1[m], 0.0f);
        }
    }
    __syncthreads();
    // ---- FF2 + residual + LN1 + output ----
    {
        float acc[NB];
        float bo = ff_b2[j];
        #pragma unroll
        for (int m = 0; m < NB; ++m) acc[m] = bo;
        #pragma unroll 4
        for (int k = 0; k < H2; ++k) {
            float s[NB];
            ld8(&hT[k][0], s);
            float wv = ff_w2[(size_t)k * D + j];
            #pragma unroll
            for (int m = 0; m < NB; ++m) acc[m] = fmaf(s[m], wv, acc[m]);
        }
        #pragma unroll
        for (int m = 0; m < NB; ++m) acc[m] += sreg[m];
        ln8(acc, ln_g + D, ln_b + D, red, j, lane, wid);
        #pragma unroll
        for (int m = 0; m < NB; ++m)
            out[(size_t)(n0 + m) * D + j] = actC[m] ? acc[m] : 0.0f;
    }
    if (j < NB) out[(size_t)NN * D + n0 + j] = actC[j] ? 1.0f : 0.0f;
}

extern "C" void kernel_launch(void* const* d_in, const int* in_sizes, int n_in,
                              void* d_out, int out_size, void* d_ws, size_t ws_size,
                              hipStream_t stream) {
    const float* x       = (const float*)d_in[0];
    const float* memory  = (const float*)d_in[1];
    const int*   active  = (const int*)d_in[2];
    const float* attn_w  = (const float*)d_in[3];
    const float* attn_b  = (const float*)d_in[4];
    const float* pattn_w = (const float*)d_in[5];
    const float* pattn_b = (const float*)d_in[6];
    const float* ff_w1   = (const float*)d_in[7];
    const float* ff_b1   = (const float*)d_in[8];
    const float* ff_w2   = (const float*)d_in[9];
    const float* ff_b2   = (const float*)d_in[10];
    const float* ln_g    = (const float*)d_in[11];
    const float* ln_b    = (const float*)d_in[12];
    float* out = (float*)d_out;

    float* ws = (float*)d_ws;
    float* Q1 = ws;
    float* K1 = ws + (size_t)NN * D;
    float* V1 = ws + 2 * (size_t)NN * D;
    float* K2 = ws + 3 * (size_t)NN * D;
    float* V2 = ws + 4 * (size_t)NN * D;

    hipLaunchKernelGGL(proj_kernel, dim3(NN / NB), dim3(D), 0, stream,
                       x, memory, active, attn_w, attn_b, pattn_w, pattn_b,
                       Q1, K1, V1, K2, V2);
    hipLaunchKernelGGL(attn_kernel, dim3(NN / NB), dim3(D), 0, stream,
                       x, active, attn_w, attn_b, pattn_w, pattn_b,
                       ff_w1, ff_b1, ff_w2, ff_b2, ln_g, ln_b,
                       Q1, K1, V1, K2, V2, out);
}

// Round 3
// 243.982 us; speedup vs baseline: 1.4588x; 1.4588x over previous
//
#include <hip/hip_runtime.h>
#include <math.h>

#define D 256
#define H2 512
#define HEADS 8
#define DH 32
#define L 25
#define GH 64
#define GW 64
#define NN 4096
#define NB 8          // nodes per block
#define PAD 12        // LDS row stride in floats (48B, 16B-aligned rows)
#define EPS 1e-5f
#define SCALE 0.17677669529663687f  // 1/sqrt(32)

__device__ __forceinline__ bool act_at(const int* __restrict__ active, int h, int w) {
    if (h < 0 || h >= GH || w < 0 || w >= GW) return false;
    if (h == 2 && w == 2) return false;   // ap.at[:, center, center].set(False) quirk
    return active[h * GW + w] != 0;
}

__device__ __forceinline__ void ld8(const float* __restrict__ row, float* s) {
    float4 a = *(const float4*)row;
    float4 b = *(const float4*)(row + 4);
    s[0] = a.x; s[1] = a.y; s[2] = a.z; s[3] = a.w;
    s[4] = b.x; s[5] = b.y; s[6] = b.z; s[7] = b.w;
}

// batched 8-row layernorm; v[m] = this thread's (col j) value for node m.
__device__ __forceinline__ void ln8(float* v, const float* __restrict__ g,
                                    const float* __restrict__ b,
                                    float (*red)[12], int j) {
    const int lane = j & 63, wid = j >> 6;
    float gg = g[j], bb = b[j];
    #pragma unroll
    for (int m = 0; m < NB; ++m) {
        float s1 = v[m], s2 = v[m] * v[m];
        #pragma unroll
        for (int off = 32; off > 0; off >>= 1) {
            s1 += __shfl_down(s1, off);
            s2 += __shfl_down(s2, off);
        }
        if (lane == 0) { red[m][wid] = s1; red[m][4 + wid] = s2; }
    }
    __syncthreads();
    if (j < NB) {
        float s1 = red[j][0] + red[j][1] + red[j][2] + red[j][3];
        float s2 = red[j][4] + red[j][5] + red[j][6] + red[j][7];
        float mu = s1 * (1.0f / D);
        float var = s2 * (1.0f / D) - mu * mu;
        red[j][8] = mu;
        red[j][9] = rsqrtf(var + EPS);
    }
    __syncthreads();
    #pragma unroll
    for (int m = 0; m < NB; ++m)
        v[m] = (v[m] - red[m][8]) * red[m][9] * gg + bb;
}

// ---------------- Kernel: batched projections ----------------
__global__ __launch_bounds__(256)
void proj_kernel(const float* __restrict__ x,
                 const float* __restrict__ mem,
                 const int* __restrict__ active,
                 const float* __restrict__ attn_w,
                 const float* __restrict__ attn_b,
                 const float* __restrict__ pattn_w,
                 const float* __restrict__ pattn_b,
                 float* __restrict__ Q1, float* __restrict__ K1, float* __restrict__ V1,
                 float* __restrict__ K2, float* __restrict__ V2) {
    const int n0 = blockIdx.x * NB;
    const int j = threadIdx.x;
    __shared__ float xT[D][PAD];
    __shared__ float mT[D][PAD];
    #pragma unroll
    for (int m = 0; m < NB; ++m) {
        int n = n0 + m;
        bool a = act_at(active, n / GW, n % GW);
        xT[j][m] = a ? x[(size_t)n * D + j] : 0.0f;
        mT[j][m] = mem[(size_t)n * D + j];
    }
    __syncthreads();

    const float* Wq  = attn_w;
    const float* Wk  = attn_w + D * D;
    const float* Wv  = attn_w + 2 * D * D;
    const float* Wk2 = pattn_w + D * D;
    const float* Wv2 = pattn_w + 2 * D * D;

    float aq[NB], ak[NB], av[NB];
    {
        float bq = attn_b[j], bk = attn_b[D + j], bv = attn_b[2 * D + j];
        #pragma unroll
        for (int m = 0; m < NB; ++m) { aq[m] = bq; ak[m] = bk; av[m] = bv; }
    }
    #pragma unroll 4
    for (int i = 0; i < D; ++i) {
        float s[NB];
        ld8(&xT[i][0], s);
        float wq = Wq[i * D + j], wk = Wk[i * D + j], wv = Wv[i * D + j];
        #pragma unroll
        for (int m = 0; m < NB; ++m) {
            aq[m] = fmaf(s[m], wq, aq[m]);
            ak[m] = fmaf(s[m], wk, ak[m]);
            av[m] = fmaf(s[m], wv, av[m]);
        }
    }
    #pragma unroll
    for (int m = 0; m < NB; ++m) {
        Q1[(size_t)(n0 + m) * D + j] = aq[m];
        K1[(size_t)(n0 + m) * D + j] = ak[m];
        V1[(size_t)(n0 + m) * D + j] = av[m];
    }

    float k2[NB], v2[NB];
    {
        float bk = pattn_b[D + j], bv = pattn_b[2 * D + j];
        #pragma unroll
        for (int m = 0; m < NB; ++m) { k2[m] = bk; v2[m] = bv; }
    }
    #pragma unroll 4
    for (int i = 0; i < D; ++i) {
        float s[NB];
        ld8(&mT[i][0], s);
        float wk = Wk2[i * D + j], wv = Wv2[i * D + j];
        #pragma unroll
        for (int m = 0; m < NB; ++m) {
            k2[m] = fmaf(s[m], wk, k2[m]);
            v2[m] = fmaf(s[m], wv, v2[m]);
        }
    }
    #pragma unroll
    for (int m = 0; m < NB; ++m) {
        K2[(size_t)(n0 + m) * D + j] = k2[m];
        V2[(size_t)(n0 + m) * D + j] = v2[m];
    }
}

// ---------------- generic batched GEMV (+ optional residual / LN) ----------------
template<bool DO_LN>
__global__ __launch_bounds__(256)
void gemv8_kernel(const float* __restrict__ In, const float* __restrict__ W,
                  const float* __restrict__ bias_, const float* __restrict__ resid,
                  const float* __restrict__ g, const float* __restrict__ b,
                  float* __restrict__ Out) {
    const int n0 = blockIdx.x * NB;
    const int j = threadIdx.x;
    __shared__ float inT[D][PAD];
    __shared__ float red[NB][12];
    #pragma unroll
    for (int m = 0; m < NB; ++m)
        inT[j][m] = In[(size_t)(n0 + m) * D + j];
    __syncthreads();

    float acc[NB];
    {
        float bv = bias_[j];
        #pragma unroll
        for (int m = 0; m < NB; ++m) acc[m] = bv;
    }
    #pragma unroll 8
    for (int i = 0; i < D; ++i) {
        float s[NB];
        ld8(&inT[i][0], s);
        float wv = W[i * D + j];
        #pragma unroll
        for (int m = 0; m < NB; ++m) acc[m] = fmaf(s[m], wv, acc[m]);
    }
    if (resid) {
        #pragma unroll
        for (int m = 0; m < NB; ++m) acc[m] += resid[(size_t)(n0 + m) * D + j];
    }
    if (DO_LN) ln8(acc, g, b, red, j);
    #pragma unroll
    for (int m = 0; m < NB; ++m)
        Out[(size_t)(n0 + m) * D + j] = acc[m];
}

// ---------------- attn1: masked scores + softmax + PV ----------------
// Writes T1 in place over Q1 (own rows only; safe: Q1 row n read only by node n's
// score phase, which completes before the PV write barrier).
__global__ __launch_bounds__(256)
void attn1_kernel(const int* __restrict__ active,
                  const float* __restrict__ Q1, const float* __restrict__ K1,
                  const float* __restrict__ V1,
                  float* __restrict__ T1) {
    const int n0 = blockIdx.x * NB;
    const int j = threadIdx.x;
    __shared__ float sc[NB][HEADS][L + 1];
    __shared__ int   nbIdx[NB][L];
    __shared__ unsigned char val1[NB][L];

    if (j < NB * L) {
        int m = j / L, l = j - m * L;
        int n = n0 + m, h = n / GW, w = n % GW;
        int hh = h + l / 5 - 2, ww = w + l % 5 - 2;
        bool ib = (hh >= 0 && hh < GH && ww >= 0 && ww < GW);
        nbIdx[m][l] = ib ? hh * GW + ww : -1;
        val1[m][l] = act_at(active, hh, ww) ? 1 : 0;
    }
    __syncthreads();

    for (int t = j; t < NB * HEADS * L; t += 256) {
        int m = t / (HEADS * L);
        int r = t - m * HEADS * L;
        int hd = r / L, l = r - hd * L;
        float s = -1e30f;
        if (val1[m][l]) {
            const float4* q = (const float4*)(Q1 + (size_t)(n0 + m) * D + hd * DH);
            const float4* k = (const float4*)(K1 + (size_t)nbIdx[m][l] * D + hd * DH);
            float acc = 0.0f;
            #pragma unroll
            for (int d = 0; d < DH / 4; ++d) {
                float4 qa = q[d], ka = k[d];
                acc = fmaf(qa.x, ka.x, acc); acc = fmaf(qa.y, ka.y, acc);
                acc = fmaf(qa.z, ka.z, acc); acc = fmaf(qa.w, ka.w, acc);
            }
            s = acc * SCALE;
        }
        sc[m][hd][l] = s;
    }
    __syncthreads();
    if (j < NB * HEADS) {
        int m = j / HEADS, hd = j - m * HEADS;
        float mx = -1e30f;
        for (int l = 0; l < L; ++l) mx = fmaxf(mx, sc[m][hd][l]);
        float sum = 0.0f;
        for (int l = 0; l < L; ++l) sum += expf(sc[m][hd][l] - mx);
        float inv = 1.0f / sum;
        for (int l = 0; l < L; ++l) sc[m][hd][l] = expf(sc[m][hd][l] - mx) * inv;
    }
    __syncthreads();
    {
        const int hd = j >> 5;
        float o[NB];
        #pragma unroll
        for (int m = 0; m < NB; ++m) o[m] = 0.0f;
        for (int m = 0; m < NB; ++m)
            for (int l = 0; l < L; ++l)
                if (val1[m][l])
                    o[m] = fmaf(sc[m][hd][l], V1[(size_t)nbIdx[m][l] * D + j], o[m]);
        #pragma unroll
        for (int m = 0; m < NB; ++m)
            T1[(size_t)(n0 + m) * D + j] = o[m];
    }
}

// ---------------- attn2: unmasked scores (OOB -> bias K/V) ----------------
__global__ __launch_bounds__(256)
void attn2_kernel(const float* __restrict__ T2, const float* __restrict__ K2,
                  const float* __restrict__ V2, const float* __restrict__ pattn_b,
                  float* __restrict__ T3) {
    const int n0 = blockIdx.x * NB;
    const int j = threadIdx.x;
    __shared__ float sc[NB][HEADS][L + 1];
    __shared__ int   nbIdx[NB][L];

    if (j < NB * L) {
        int m = j / L, l = j - m * L;
        int n = n0 + m, h = n / GW, w = n % GW;
        int hh = h + l / 5 - 2, ww = w + l % 5 - 2;
        bool ib = (hh >= 0 && hh < GH && ww >= 0 && ww < GW);
        nbIdx[m][l] = ib ? hh * GW + ww : -1;
    }
    __syncthreads();

    for (int t = j; t < NB * HEADS * L; t += 256) {
        int m = t / (HEADS * L);
        int r = t - m * HEADS * L;
        int hd = r / L, l = r - hd * L;
        int nb = nbIdx[m][l];
        const float4* q = (const float4*)(T2 + (size_t)(n0 + m) * D + hd * DH);
        const float4* k = (nb >= 0) ? (const float4*)(K2 + (size_t)nb * D + hd * DH)
                                    : (const float4*)(pattn_b + D + hd * DH);
        float acc = 0.0f;
        #pragma unroll
        for (int d = 0; d < DH / 4; ++d) {
            float4 qa = q[d], ka = k[d];
            acc = fmaf(qa.x, ka.x, acc); acc = fmaf(qa.y, ka.y, acc);
            acc = fmaf(qa.z, ka.z, acc); acc = fmaf(qa.w, ka.w, acc);
        }
        sc[m][hd][l] = acc * SCALE;
    }
    __syncthreads();
    if (j < NB * HEADS) {
        int m = j / HEADS, hd = j - m * HEADS;
        float mx = -1e30f;
        for (int l = 0; l < L; ++l) mx = fmaxf(mx, sc[m][hd][l]);
        float sum = 0.0f;
        for (int l = 0; l < L; ++l) sum += expf(sc[m][hd][l] - mx);
        float inv = 1.0f / sum;
        for (int l = 0; l < L; ++l) sc[m][hd][l] = expf(sc[m][hd][l] - mx) * inv;
    }
    __syncthreads();
    {
        const int hd = j >> 5;
        float bvv = pattn_b[2 * D + j];
        float o[NB];
        #pragma unroll
        for (int m = 0; m < NB; ++m) o[m] = 0.0f;
        for (int m = 0; m < NB; ++m)
            for (int l = 0; l < L; ++l) {
                int nb = nbIdx[m][l];
                float vv = (nb >= 0) ? V2[(size_t)nb * D + j] : bvv;
                o[m] = fmaf(sc[m][hd][l], vv, o[m]);
            }
        #pragma unroll
        for (int m = 0; m < NB; ++m)
            T3[(size_t)(n0 + m) * D + j] = o[m];
    }
}

// ---------------- FF1: 256 -> 512 + ReLU ----------------
__global__ __launch_bounds__(256)
void ff1_kernel(const float* __restrict__ In, const float* __restrict__ W1,
                const float* __restrict__ b1, float* __restrict__ Hout) {
    const int n0 = blockIdx.x * NB;
    const int j = threadIdx.x;
    __shared__ float inT[D][PAD];
    #pragma unroll
    for (int m = 0; m < NB; ++m)
        inT[j][m] = In[(size_t)(n0 + m) * D + j];
    __syncthreads();

    float a0[NB], a1[NB];
    {
        float b0 = b1[j], bb1 = b1[j + D];
        #pragma unroll
        for (int m = 0; m < NB; ++m) { a0[m] = b0; a1[m] = bb1; }
    }
    #pragma unroll 8
    for (int i = 0; i < D; ++i) {
        float s[NB];
        ld8(&inT[i][0], s);
        float w0 = W1[(size_t)i * H2 + j];
        float w1 = W1[(size_t)i * H2 + j + D];
        #pragma unroll
        for (int m = 0; m < NB; ++m) {
            a0[m] = fmaf(s[m], w0, a0[m]);
            a1[m] = fmaf(s[m], w1, a1[m]);
        }
    }
    #pragma unroll
    for (int m = 0; m < NB; ++m) {
        Hout[(size_t)(n0 + m) * H2 + j]     = fmaxf(a0[m], 0.0f);
        Hout[(size_t)(n0 + m) * H2 + j + D] = fmaxf(a1[m], 0.0f);
    }
}

// ---------------- FF2: 512 -> 256 + residual + LN + mask + flags ----------------
__global__ __launch_bounds__(256)
void ff2_kernel(const float* __restrict__ Hin, const float* __restrict__ W2,
                const float* __restrict__ b2, const float* __restrict__ resid,
                const float* __restrict__ g, const float* __restrict__ b,
                const int* __restrict__ active, float* __restrict__ out) {
    const int n0 = blockIdx.x * NB;
    const int j = threadIdx.x;
    __shared__ float inT[H2][PAD];
    __shared__ float red[NB][12];
    #pragma unroll
    for (int r = 0; r < 2; ++r)
        #pragma unroll
        for (int m = 0; m < NB; ++m)
            inT[r * D + j][m] = Hin[(size_t)(n0 + m) * H2 + r * D + j];
    __syncthreads();

    float acc[NB];
    {
        float bv = b2[j];
        #pragma unroll
        for (int m = 0; m < NB; ++m) acc[m] = bv;
    }
    #pragma unroll 8
    for (int k = 0; k < H2; ++k) {
        float s[NB];
        ld8(&inT[k][0], s);
        float wv = W2[(size_t)k * D + j];
        #pragma unroll
        for (int m = 0; m < NB; ++m) acc[m] = fmaf(s[m], wv, acc[m]);
    }
    #pragma unroll
    for (int m = 0; m < NB; ++m) acc[m] += resid[(size_t)(n0 + m) * D + j];
    ln8(acc, g, b, red, j);
    #pragma unroll
    for (int m = 0; m < NB; ++m) {
        int n = n0 + m;
        bool a = act_at(active, n / GW, n % GW);
        out[(size_t)n * D + j] = a ? acc[m] : 0.0f;
    }
    if (j < NB) {
        int n = n0 + j;
        out[(size_t)NN * D + n] = act_at(active, n / GW, n % GW) ? 1.0f : 0.0f;
    }
}

extern "C" void kernel_launch(void* const* d_in, const int* in_sizes, int n_in,
                              void* d_out, int out_size, void* d_ws, size_t ws_size,
                              hipStream_t stream) {
    const float* x       = (const float*)d_in[0];
    const float* memory  = (const float*)d_in[1];
    const int*   active  = (const int*)d_in[2];
    const float* attn_w  = (const float*)d_in[3];
    const float* attn_b  = (const float*)d_in[4];
    const float* pattn_w = (const float*)d_in[5];
    const float* pattn_b = (const float*)d_in[6];
    const float* ff_w1   = (const float*)d_in[7];
    const float* ff_b1   = (const float*)d_in[8];
    const float* ff_w2   = (const float*)d_in[9];
    const float* ff_b2   = (const float*)d_in[10];
    const float* ln_g    = (const float*)d_in[11];
    const float* ln_b    = (const float*)d_in[12];
    float* out = (float*)d_out;

    const size_t NND = (size_t)NN * D;
    float* ws = (float*)d_ws;
    float* s0 = ws;            // Q1 -> T1 -> T3
    float* s1 = ws + NND;      // K1 -> S  -> S2 (in-place)
    float* s2 = ws + 2 * NND;  // V1 -> T2
    float* s3 = ws + 3 * NND;  // K2 -> H (low half; H spans s3..s4)
    float* s4 = ws + 4 * NND;  // V2 -> H (high half)

    const int G = NN / NB;
    hipLaunchKernelGGL(proj_kernel, dim3(G), dim3(D), 0, stream,
                       x, memory, active, attn_w, attn_b, pattn_w, pattn_b,
                       s0, s1, s2, s3, s4);
    hipLaunchKernelGGL(attn1_kernel, dim3(G), dim3(D), 0, stream,
                       active, s0, s1, s2, s0);
    // S = LN0( T1 @ Wo1 + bo1 + x )
    hipLaunchKernelGGL(gemv8_kernel<true>, dim3(G), dim3(D), 0, stream,
                       s0, attn_w + 3 * D * D, attn_b + 3 * D, x, ln_g, ln_b, s1);
    // T2 = S @ Wq2 + bq2
    hipLaunchKernelGGL(gemv8_kernel<false>, dim3(G), dim3(D), 0, stream,
                       s1, pattn_w, pattn_b, (const float*)nullptr,
                       (const float*)nullptr, (const float*)nullptr, s2);
    hipLaunchKernelGGL(attn2_kernel, dim3(G), dim3(D), 0, stream,
                       s2, s3, s4, pattn_b, s0);
    // S2 = LN2( T3 @ Wo2 + bo2 + S )   (in place over S)
    hipLaunchKernelGGL(gemv8_kernel<true>, dim3(G), dim3(D), 0, stream,
                       s0, pattn_w + 3 * D * D, pattn_b + 3 * D, s1,
                       ln_g + 2 * D, ln_b + 2 * D, s1);
    hipLaunchKernelGGL(ff1_kernel, dim3(G), dim3(D), 0, stream,
                       s1, ff_w1, ff_b1, s3);
    hipLaunchKernelGGL(ff2_kernel, dim3(G), dim3(D), 0, stream,
                       s3, ff_w2, ff_b2, s1, ln_g + D, ln_b + D, active, out);
}

// Round 4
// 194.411 us; speedup vs baseline: 1.8307x; 1.2550x over previous
//
#include <hip/hip_runtime.h>
#include <math.h>

#define D 256
#define H2 512
#define HEADS 8
#define DH 32
#define L 25
#define GH 64
#define GW 64
#define NN 4096
#define NB 8          // nodes per block (stage2/3)
#define NB2 16        // nodes per block (proj)
#define PAD 12        // LDS row stride floats (48B, 16B-aligned)
#define PAD2 20       // LDS row stride floats for 16-node rows (80B)
#define EPS 1e-5f
#define SCALE 0.17677669529663687f  // 1/sqrt(32)

__device__ __forceinline__ bool act_at(const int* __restrict__ active, int h, int w) {
    if (h < 0 || h >= GH || w < 0 || w >= GW) return false;
    if (h == 2 && w == 2) return false;   // ap.at[:, center, center].set(False) quirk
    return active[h * GW + w] != 0;
}

__device__ __forceinline__ void ld8(const float* __restrict__ row, float* s) {
    float4 a = *(const float4*)row;
    float4 b = *(const float4*)(row + 4);
    s[0]=a.x; s[1]=a.y; s[2]=a.z; s[3]=a.w;
    s[4]=b.x; s[5]=b.y; s[6]=b.z; s[7]=b.w;
}
__device__ __forceinline__ void ld16(const float* __restrict__ row, float* s) {
    #pragma unroll
    for (int q = 0; q < 4; ++q) {
        float4 a = *(const float4*)(row + 4 * q);
        s[4*q]=a.x; s[4*q+1]=a.y; s[4*q+2]=a.z; s[4*q+3]=a.w;
    }
}

// ---------------- proj: one block per (16-node group, weight stream) ----------------
__global__ __launch_bounds__(256)
void proj_kernel(const float* __restrict__ x,
                 const float* __restrict__ mem,
                 const int* __restrict__ active,
                 const float* __restrict__ attn_w,
                 const float* __restrict__ attn_b,
                 const float* __restrict__ pattn_w,
                 const float* __restrict__ pattn_b,
                 float* __restrict__ Q1, float* __restrict__ K1, float* __restrict__ V1,
                 float* __restrict__ K2, float* __restrict__ V2) {
    const int s = blockIdx.x >> 8;        // stream 0..4
    const int g = blockIdx.x & 255;       // node group
    const int n0 = g * NB2;
    const int j = threadIdx.x;
    __shared__ float inT[D][PAD2];

    const float* src = (s < 3) ? x : mem;
    const bool maskin = (s < 3);
    #pragma unroll
    for (int m = 0; m < NB2; ++m) {
        int n = n0 + m;
        float v = src[(size_t)n * D + j];
        if (maskin && !act_at(active, n / GW, n % GW)) v = 0.0f;
        inT[j][m] = v;
    }
    __syncthreads();

    const float* W; const float* bi; float* outp;
    switch (s) {
      case 0:  W = attn_w;               bi = attn_b;           outp = Q1; break;
      case 1:  W = attn_w + D * D;       bi = attn_b + D;       outp = K1; break;
      case 2:  W = attn_w + 2 * D * D;   bi = attn_b + 2 * D;   outp = V1; break;
      case 3:  W = pattn_w + D * D;      bi = pattn_b + D;      outp = K2; break;
      default: W = pattn_w + 2 * D * D;  bi = pattn_b + 2 * D;  outp = V2; break;
    }

    float acc[NB2];
    {
        float bv = bi[j];
        #pragma unroll
        for (int m = 0; m < NB2; ++m) acc[m] = bv;
    }
    #pragma unroll 4
    for (int i = 0; i < D; ++i) {
        float sv[NB2];
        ld16(&inT[i][0], sv);
        float wv = W[i * D + j];
        #pragma unroll
        for (int m = 0; m < NB2; ++m) acc[m] = fmaf(sv[m], wv, acc[m]);
    }
    #pragma unroll
    for (int m = 0; m < NB2; ++m)
        outp[(size_t)(n0 + m) * D + j] = acc[m];
}

// ---------------- stage2: scores1+softmax+PV1 + Wo1+LN0 + Wq2 ----------------
__global__ __launch_bounds__(512)
void stage2_kernel(const float* __restrict__ x, const int* __restrict__ active,
                   const float* __restrict__ attn_w, const float* __restrict__ attn_b,
                   const float* __restrict__ pattn_w, const float* __restrict__ pattn_b,
                   const float* __restrict__ ln_g, const float* __restrict__ ln_b,
                   const float* __restrict__ Q1, const float* __restrict__ K1,
                   const float* __restrict__ V1,
                   float* __restrict__ Sbuf, float* __restrict__ T2) {
    const int n0 = blockIdx.x * NB;
    const int tid = threadIdx.x;
    const int j = tid & (D - 1);
    const int kh = tid >> 8;          // split-K half: 0 or 1

    __shared__ float sc[NB][HEADS][L + 1];
    __shared__ int   nbIdx[NB][L];
    __shared__ unsigned char val1[NB][L];
    __shared__ float tT[D][PAD];
    __shared__ float pT[D][PAD];
    __shared__ float sT[D][PAD];
    __shared__ float red[NB][12];

    if (tid < NB * L) {
        int m = tid / L, l = tid - m * L;
        int n = n0 + m, h = n / GW, w = n % GW;
        int hh = h + l / 5 - 2, ww = w + l % 5 - 2;
        bool ib = (hh >= 0 && hh < GH && ww >= 0 && ww < GW);
        nbIdx[m][l] = ib ? hh * GW + ww : -1;
        val1[m][l] = act_at(active, hh, ww) ? 1 : 0;
    }
    __syncthreads();

    // scores (masked)
    for (int t = tid; t < NB * HEADS * L; t += 512) {
        int m = t / (HEADS * L);
        int r = t - m * (HEADS * L);
        int hd = r / L, l = r - hd * L;
        float sv = -1e30f;
        if (val1[m][l]) {
            const float4* q = (const float4*)(Q1 + (size_t)(n0 + m) * D + hd * DH);
            const float4* k = (const float4*)(K1 + (size_t)nbIdx[m][l] * D + hd * DH);
            float a = 0.0f;
            #pragma unroll
            for (int d = 0; d < DH / 4; ++d) {
                float4 qa = q[d], ka = k[d];
                a = fmaf(qa.x, ka.x, a); a = fmaf(qa.y, ka.y, a);
                a = fmaf(qa.z, ka.z, a); a = fmaf(qa.w, ka.w, a);
            }
            sv = a * SCALE;
        }
        sc[m][hd / 1][l] = sv;
    }
    __syncthreads();
    if (tid < NB * HEADS) {
        int m = tid / HEADS, hd = tid - m * HEADS;
        float mx = -1e30f;
        for (int l = 0; l < L; ++l) mx = fmaxf(mx, sc[m][hd][l]);
        float sum = 0.0f;
        for (int l = 0; l < L; ++l) { float e = expf(sc[m][hd][l] - mx); sc[m][hd][l] = e; sum += e; }
        float inv = 1.0f / sum;
        for (int l = 0; l < L; ++l) sc[m][hd][l] *= inv;
    }
    __syncthreads();
    // PV1 -> tT (half handles 4 nodes)
    {
        const int hd = j >> 5;
        const int mb = kh * 4;
        float o[4] = {0.f, 0.f, 0.f, 0.f};
        for (int l = 0; l < L; ++l) {
            #pragma unroll
            for (int mm = 0; mm < 4; ++mm) {
                int m = mb + mm;
                if (val1[m][l])
                    o[mm] = fmaf(sc[m][hd][l], V1[(size_t)nbIdx[m][l] * D + j], o[mm]);
            }
        }
        #pragma unroll
        for (int mm = 0; mm < 4; ++mm) tT[j][mb + mm] = o[mm];
    }
    __syncthreads();

    // Wo1 split-K + resid + LN0 -> sT, Sbuf
    float acc[NB];
    {
        float b0 = (kh == 0) ? attn_b[3 * D + j] : 0.0f;
        #pragma unroll
        for (int m = 0; m < NB; ++m) acc[m] = b0;
        const float* Wo1 = attn_w + 3 * D * D;
        const int i0 = kh * (D / 2);
        #pragma unroll 8
        for (int ii = 0; ii < D / 2; ++ii) {
            int i = i0 + ii;
            float s8[NB]; ld8(&tT[i][0], s8);
            float wv = Wo1[i * D + j];
            #pragma unroll
            for (int m = 0; m < NB; ++m) acc[m] = fmaf(s8[m], wv, acc[m]);
        }
    }
    if (kh == 1) {
        #pragma unroll
        for (int m = 0; m < NB; ++m) pT[j][m] = acc[m];
    }
    __syncthreads();
    if (kh == 0) {
        #pragma unroll
        for (int m = 0; m < NB; ++m) {
            acc[m] += pT[j][m] + x[(size_t)(n0 + m) * D + j];
            float s1 = acc[m], s2 = acc[m] * acc[m];
            #pragma unroll
            for (int off = 32; off > 0; off >>= 1) {
                s1 += __shfl_down(s1, off);
                s2 += __shfl_down(s2, off);
            }
            if ((j & 63) == 0) { red[m][j >> 6] = s1; red[m][4 + (j >> 6)] = s2; }
        }
    }
    __syncthreads();
    if (tid < NB) {
        float s1 = red[tid][0] + red[tid][1] + red[tid][2] + red[tid][3];
        float s2 = red[tid][4] + red[tid][5] + red[tid][6] + red[tid][7];
        float mu = s1 * (1.0f / D);
        float var = s2 * (1.0f / D) - mu * mu;
        red[tid][8] = mu;
        red[tid][9] = rsqrtf(var + EPS);
    }
    __syncthreads();
    if (kh == 0) {
        float gg = ln_g[j], bb = ln_b[j];
        #pragma unroll
        for (int m = 0; m < NB; ++m) {
            float v = (acc[m] - red[m][8]) * red[m][9] * gg + bb;
            sT[j][m] = v;
            Sbuf[(size_t)(n0 + m) * D + j] = v;
        }
    }
    __syncthreads();

    // Wq2 split-K -> T2 (staged in d_out)
    {
        float b0 = (kh == 0) ? pattn_b[j] : 0.0f;
        #pragma unroll
        for (int m = 0; m < NB; ++m) acc[m] = b0;
        const int i0 = kh * (D / 2);
        #pragma unroll 8
        for (int ii = 0; ii < D / 2; ++ii) {
            int i = i0 + ii;
            float s8[NB]; ld8(&sT[i][0], s8);
            float wv = pattn_w[i * D + j];
            #pragma unroll
            for (int m = 0; m < NB; ++m) acc[m] = fmaf(s8[m], wv, acc[m]);
        }
    }
    if (kh == 1) {
        #pragma unroll
        for (int m = 0; m < NB; ++m) pT[j][m] = acc[m];
    }
    __syncthreads();
    if (kh == 0) {
        #pragma unroll
        for (int m = 0; m < NB; ++m)
            T2[(size_t)(n0 + m) * D + j] = acc[m] + pT[j][m];
    }
}

// ---------------- stage3: scores2+softmax+PV2 + Wo2+LN2 + FF1 + FF2+LN1 ----------------
// LDS layout (manual aliasing; hT reuses the dead sc/idx/tT/pT region):
#define SC_OFF   0            // 8*8*26*4 = 6656
#define IDX_OFF  6656         // 800
#define TT_OFF   7456         // 12288
#define PT_OFF   19744        // 12288
#define ST_OFF   32032        // 12288
#define RED_OFF  44320        // 384
#define PT2_OFF  44704        // 12288
#define ACT_OFF  56992        // 32
#define SMEM3_SZ 57024
#define HT_OFF   0            // 512*12*4 = 24576 (aliases SC..part of PT)

__global__ __launch_bounds__(512)
void stage3_kernel(const int* __restrict__ active,
                   const float* __restrict__ pattn_w, const float* __restrict__ pattn_b,
                   const float* __restrict__ ff_w1, const float* __restrict__ ff_b1,
                   const float* __restrict__ ff_w2, const float* __restrict__ ff_b2,
                   const float* __restrict__ ln_g, const float* __restrict__ ln_b,
                   const float* __restrict__ K2, const float* __restrict__ V2,
                   const float* __restrict__ Sbuf, const float* __restrict__ T2,
                   float* __restrict__ out) {
    const int n0 = blockIdx.x * NB;
    const int tid = threadIdx.x;
    const int j = tid & (D - 1);
    const int kh = tid >> 8;

    __shared__ __align__(16) char smem[SMEM3_SZ];
    float (*sc)[HEADS][L + 1] = (float(*)[HEADS][L + 1])(smem + SC_OFF);
    int   (*nbIdx)[L]         = (int(*)[L])(smem + IDX_OFF);
    float (*tT)[PAD]          = (float(*)[PAD])(smem + TT_OFF);
    float (*pT)[PAD]          = (float(*)[PAD])(smem + PT_OFF);
    float (*sT)[PAD]          = (float(*)[PAD])(smem + ST_OFF);
    float (*red)[12]          = (float(*)[12])(smem + RED_OFF);
    float (*pT2)[PAD]         = (float(*)[PAD])(smem + PT2_OFF);
    int*  actC                = (int*)(smem + ACT_OFF);
    float (*hT)[PAD]          = (float(*)[PAD])(smem + HT_OFF);

    if (tid < NB * L) {
        int m = tid / L, l = tid - m * L;
        int n = n0 + m, h = n / GW, w = n % GW;
        int hh = h + l / 5 - 2, ww = w + l % 5 - 2;
        bool ib = (hh >= 0 && hh < GH && ww >= 0 && ww < GW);
        nbIdx[m][l] = ib ? hh * GW + ww : -1;
    }
    if (tid < NB) {
        int n = n0 + tid;
        actC[tid] = act_at(active, n / GW, n % GW) ? 1 : 0;
    }
    __syncthreads();

    // scores2 (unmasked; OOB -> bias-only K)
    for (int t = tid; t < NB * HEADS * L; t += 512) {
        int m = t / (HEADS * L);
        int r = t - m * (HEADS * L);
        int hd = r / L, l = r - hd * L;
        int nb = nbIdx[m][l];
        const float4* q = (const float4*)(T2 + (size_t)(n0 + m) * D + hd * DH);
        const float4* k = (nb >= 0) ? (const float4*)(K2 + (size_t)nb * D + hd * DH)
                                    : (const float4*)(pattn_b + D + hd * DH);
        float a = 0.0f;
        #pragma unroll
        for (int d = 0; d < DH / 4; ++d) {
            float4 qa = q[d], ka = k[d];
            a = fmaf(qa.x, ka.x, a); a = fmaf(qa.y, ka.y, a);
            a = fmaf(qa.z, ka.z, a); a = fmaf(qa.w, ka.w, a);
        }
        sc[m][hd][l] = a * SCALE;
    }
    __syncthreads();
    if (tid < NB * HEADS) {
        int m = tid / HEADS, hd = tid - m * HEADS;
        float mx = -1e30f;
        for (int l = 0; l < L; ++l) mx = fmaxf(mx, sc[m][hd][l]);
        float sum = 0.0f;
        for (int l = 0; l < L; ++l) { float e = expf(sc[m][hd][l] - mx); sc[m][hd][l] = e; sum += e; }
        float inv = 1.0f / sum;
        for (int l = 0; l < L; ++l) sc[m][hd][l] *= inv;
    }
    __syncthreads();
    // PV2 -> tT
    {
        const int hd = j >> 5;
        const int mb = kh * 4;
        float bvv = pattn_b[2 * D + j];
        float o[4] = {0.f, 0.f, 0.f, 0.f};
        for (int l = 0; l < L; ++l) {
            #pragma unroll
            for (int mm = 0; mm < 4; ++mm) {
                int nb = nbIdx[mb + mm][l];
                float vv = (nb >= 0) ? V2[(size_t)nb * D + j] : bvv;
                o[mm] = fmaf(sc[mb + mm][hd][l], vv, o[mm]);
            }
        }
        #pragma unroll
        for (int mm = 0; mm < 4; ++mm) tT[j][mb + mm] = o[mm];
    }
    __syncthreads();

    // Wo2 split-K + resid(Sbuf) + LN2 -> sT
    float acc[NB];
    {
        float b0 = (kh == 0) ? pattn_b[3 * D + j] : 0.0f;
        #pragma unroll
        for (int m = 0; m < NB; ++m) acc[m] = b0;
        const float* Wo2 = pattn_w + 3 * D * D;
        const int i0 = kh * (D / 2);
        #pragma unroll 8
        for (int ii = 0; ii < D / 2; ++ii) {
            int i = i0 + ii;
            float s8[NB]; ld8(&tT[i][0], s8);
            float wv = Wo2[i * D + j];
            #pragma unroll
            for (int m = 0; m < NB; ++m) acc[m] = fmaf(s8[m], wv, acc[m]);
        }
    }
    if (kh == 1) {
        #pragma unroll
        for (int m = 0; m < NB; ++m) pT[j][m] = acc[m];
    }
    __syncthreads();
    if (kh == 0) {
        #pragma unroll
        for (int m = 0; m < NB; ++m) {
            acc[m] += pT[j][m] + Sbuf[(size_t)(n0 + m) * D + j];
            float s1 = acc[m], s2 = acc[m] * acc[m];
            #pragma unroll
            for (int off = 32; off > 0; off >>= 1) {
                s1 += __shfl_down(s1, off);
                s2 += __shfl_down(s2, off);
            }
            if ((j & 63) == 0) { red[m][j >> 6] = s1; red[m][4 + (j >> 6)] = s2; }
        }
    }
    __syncthreads();
    if (tid < NB) {
        float s1 = red[tid][0] + red[tid][1] + red[tid][2] + red[tid][3];
        float s2 = red[tid][4] + red[tid][5] + red[tid][6] + red[tid][7];
        float mu = s1 * (1.0f / D);
        float var = s2 * (1.0f / D) - mu * mu;
        red[tid][8] = mu;
        red[tid][9] = rsqrtf(var + EPS);
    }
    __syncthreads();
    if (kh == 0) {
        float gg = ln_g[2 * D + j], bb = ln_b[2 * D + j];
        #pragma unroll
        for (int m = 0; m < NB; ++m)
            sT[j][m] = (acc[m] - red[m][8]) * red[m][9] * gg + bb;
    }
    __syncthreads();   // sT ready; sc/tT/pT dead -> hT may be written

    // FF1: each thread one hidden col c = tid
    {
        const int c = tid;
        float a1[NB];
        float b1v = ff_b1[c];
        #pragma unroll
        for (int m = 0; m < NB; ++m) a1[m] = b1v;
        #pragma unroll 8
        for (int k = 0; k < D; ++k) {
            float s8[NB]; ld8(&sT[k][0], s8);
            float wv = ff_w1[(size_t)k * H2 + c];
            #pragma unroll
            for (int m = 0; m < NB; ++m) a1[m] = fmaf(s8[m], wv, a1[m]);
        }
        #pragma unroll
        for (int m = 0; m < NB; ++m) hT[c][m] = fmaxf(a1[m], 0.0f);
    }
    __syncthreads();

    // FF2 split-K + resid(sT) + LN1 + mask -> out
    {
        float b0 = (kh == 0) ? ff_b2[j] : 0.0f;
        #pragma unroll
        for (int m = 0; m < NB; ++m) acc[m] = b0;
        const int k0 = kh * (H2 / 2);
        #pragma unroll 8
        for (int kk = 0; kk < H2 / 2; ++kk) {
            int k = k0 + kk;
            float s8[NB]; ld8(&hT[k][0], s8);
            float wv = ff_w2[(size_t)k * D + j];
            #pragma unroll
            for (int m = 0; m < NB; ++m) acc[m] = fmaf(s8[m], wv, acc[m]);
        }
    }
    if (kh == 1) {
        #pragma unroll
        for (int m = 0; m < NB; ++m) pT2[j][m] = acc[m];
    }
    __syncthreads();
    if (kh == 0) {
        #pragma unroll
        for (int m = 0; m < NB; ++m) {
            acc[m] += pT2[j][m] + sT[j][m];
            float s1 = acc[m], s2 = acc[m] * acc[m];
            #pragma unroll
            for (int off = 32; off > 0; off >>= 1) {
                s1 += __shfl_down(s1, off);
                s2 += __shfl_down(s2, off);
            }
            if ((j & 63) == 0) { red[m][j >> 6] = s1; red[m][4 + (j >> 6)] = s2; }
        }
    }
    __syncthreads();
    if (tid < NB) {
        float s1 = red[tid][0] + red[tid][1] + red[tid][2] + red[tid][3];
        float s2 = red[tid][4] + red[tid][5] + red[tid][6] + red[tid][7];
        float mu = s1 * (1.0f / D);
        float var = s2 * (1.0f / D) - mu * mu;
        red[tid][8] = mu;
        red[tid][9] = rsqrtf(var + EPS);
    }
    __syncthreads();
    if (kh == 0) {
        float gg = ln_g[D + j], bb = ln_b[D + j];
        #pragma unroll
        for (int m = 0; m < NB; ++m) {
            float v = (acc[m] - red[m][8]) * red[m][9] * gg + bb;
            out[(size_t)(n0 + m) * D + j] = actC[m] ? v : 0.0f;
        }
    }
    if (tid < NB)
        out[(size_t)NN * D + n0 + tid] = actC[tid] ? 1.0f : 0.0f;
}

extern "C" void kernel_launch(void* const* d_in, const int* in_sizes, int n_in,
                              void* d_out, int out_size, void* d_ws, size_t ws_size,
                              hipStream_t stream) {
    const float* x       = (const float*)d_in[0];
    const float* memory  = (const float*)d_in[1];
    const int*   active  = (const int*)d_in[2];
    const float* attn_w  = (const float*)d_in[3];
    const float* attn_b  = (const float*)d_in[4];
    const float* pattn_w = (const float*)d_in[5];
    const float* pattn_b = (const float*)d_in[6];
    const float* ff_w1   = (const float*)d_in[7];
    const float* ff_b1   = (const float*)d_in[8];
    const float* ff_w2   = (const float*)d_in[9];
    const float* ff_b2   = (const float*)d_in[10];
    const float* ln_g    = (const float*)d_in[11];
    const float* ln_b    = (const float*)d_in[12];
    float* out = (float*)d_out;

    const size_t NND = (size_t)NN * D;
    float* ws = (float*)d_ws;
    float* Q1 = ws;            // -> overwritten by S (own rows) in stage2
    float* K1 = ws + NND;
    float* V1 = ws + 2 * NND;
    float* K2 = ws + 3 * NND;
    float* V2 = ws + 4 * NND;
    float* Sbuf = Q1;          // S aliases Q1 (own-node rows only; safe)
    float* T2   = out;         // T2 staged in d_out rows, overwritten by final store

    hipLaunchKernelGGL(proj_kernel, dim3(5 * (NN / NB2)), dim3(D), 0, stream,
                       x, memory, active, attn_w, attn_b, pattn_w, pattn_b,
                       Q1, K1, V1, K2, V2);
    hipLaunchKernelGGL(stage2_kernel, dim3(NN / NB), dim3(512), 0, stream,
                       x, active, attn_w, attn_b, pattn_w, pattn_b, ln_g, ln_b,
                       Q1, K1, V1, Sbuf, T2);
    hipLaunchKernelGGL(stage3_kernel, dim3(NN / NB), dim3(512), 0, stream,
                       active, pattn_w, pattn_b, ff_w1, ff_b1, ff_w2, ff_b2,
                       ln_g, ln_b, K2, V2, Sbuf, T2, out);
}

// Round 5
// 184.386 us; speedup vs baseline: 1.9303x; 1.0544x over previous
//
#include <hip/hip_runtime.h>
#include <math.h>

#define D 256
#define H2 512
#define HEADS 8
#define DH 32
#define L 25
#define GH 64
#define GW 64
#define NN 4096
#define NB 8
#define EPS 1e-5f
#define SCALE 0.17677669529663687f  // 1/sqrt(32)
#define NND 1048576                 // NN*D

typedef __attribute__((ext_vector_type(8))) short short8;
typedef __attribute__((ext_vector_type(4))) float f32x4;

__device__ __forceinline__ bool act_at(const int* __restrict__ active, int h, int w) {
    if (h < 0 || h >= GH || w < 0 || w >= GW) return false;
    if (h == 2 && w == 2) return false;   // ap.at[:, center, center].set(False) quirk
    return active[h * GW + w] != 0;
}

__device__ __forceinline__ unsigned short f2b(float f) {
    unsigned u = __float_as_uint(f);
    u += 0x7fffu + ((u >> 16) & 1u);      // RNE
    return (unsigned short)(u >> 16);
}

// ---------------- prep: bf16 conversions + weight transposes ----------------
__global__ __launch_bounds__(256)
void prep_kernel(const float* __restrict__ x, const float* __restrict__ mem,
                 const int* __restrict__ active,
                 const float* __restrict__ attn_w, const float* __restrict__ pattn_w,
                 const float* __restrict__ ff_w1, const float* __restrict__ ff_w2,
                 unsigned short* __restrict__ xmB, unsigned short* __restrict__ memB,
                 unsigned short* __restrict__ wB) {
    const int TOT = 2883584;
    for (int idx = blockIdx.x * 256 + threadIdx.x; idx < TOT; idx += gridDim.x * 256) {
        if (idx < 1048576) {
            int n = idx >> 8;
            bool a = act_at(active, n >> 6, n & 63);
            xmB[idx] = f2b(a ? x[idx] : 0.0f);
        } else if (idx < 2097152) {
            int t = idx - 1048576;
            memB[t] = f2b(mem[t]);
        } else if (idx < 2621440) {
            int t = idx - 2097152;
            int s = t >> 16, r = t & 65535;
            int n = r >> 8, i = r & 255;
            const float* src = (s < 4) ? (attn_w + s * 65536) : (pattn_w + (s - 4) * 65536);
            wB[t] = f2b(src[i * 256 + n]);          // WT[s][n][i] = W[i][n]
        } else if (idx < 2752512) {
            int t = idx - 2621440;
            int c = t >> 8, i = t & 255;
            wB[524288 + t] = f2b(ff_w1[i * 512 + c]);  // W1T[c][i]
        } else {
            int t = idx - 2752512;
            int c = t >> 9, k = t & 511;
            wB[655360 + t] = f2b(ff_w2[k * 256 + c]);  // W2T[c][k]
        }
    }
}

// ---------------- generic MFMA GEMM: [4096,K]bf16 x WT[N,K]bf16 -> out ----------------
// MODE 0: outF = acc + bias (f32). MODE 1: outB = bf16(relu(acc + bias)).
template<int K, int N, int MODE>
__global__ __launch_bounds__(256)
void gemm_kernel(const unsigned short* __restrict__ A,
                 const unsigned short* __restrict__ WT,
                 const float* __restrict__ bias,
                 float* __restrict__ outF, unsigned short* __restrict__ outB) {
    const int tid = threadIdx.x;
    const int wave = tid >> 6, lane = tid & 63;
    const int m0 = blockIdx.x * 64 + wave * 16;
    const int n0 = blockIdx.y * 64;
    const int lr = lane & 15;
    const int lk = (lane >> 4) << 3;
    f32x4 acc[4] = {};
    const unsigned short* arow = A  + (size_t)(m0 + lr) * K + lk;
    const unsigned short* brow = WT + (size_t)(n0 + lr) * K + lk;
    #pragma unroll 8
    for (int kk = 0; kk < K; kk += 32) {
        short8 a = *(const short8*)(arow + kk);
        #pragma unroll
        for (int nf = 0; nf < 4; ++nf) {
            short8 b = *(const short8*)(brow + (size_t)nf * 16 * K + kk);
            acc[nf] = __builtin_amdgcn_mfma_f32_16x16x32_bf16(a, b, acc[nf], 0, 0, 0);
        }
    }
    const int rbase = m0 + ((lane >> 4) << 2);
    #pragma unroll
    for (int nf = 0; nf < 4; ++nf) {
        int c = n0 + nf * 16 + lr;
        float bc = bias[c];
        #pragma unroll
        for (int jj = 0; jj < 4; ++jj) {
            float v = acc[nf][jj] + bc;
            if (MODE == 0) outF[(size_t)(rbase + jj) * N + c] = v;
            else           outB[(size_t)(rbase + jj) * N + c] = f2b(fmaxf(v, 0.0f));
        }
    }
}

// ---------------- proj: 5 GEMM streams in one launch ----------------
__global__ __launch_bounds__(256)
void proj_gemm(const unsigned short* __restrict__ xmB,
               const unsigned short* __restrict__ memB,
               const unsigned short* __restrict__ wB,
               const float* __restrict__ attn_b, const float* __restrict__ pattn_b,
               float* __restrict__ wsf) {
    const int s  = blockIdx.y >> 2;       // 0:Q1 1:K1 2:V1 3:K2 4:V2
    const int n0 = (blockIdx.y & 3) * 64;
    const unsigned short* A  = (s < 3) ? xmB : memB;
    const int wtIdx = (s < 3) ? s : (s + 2);            // k2->5, v2->6
    const unsigned short* WT = wB + (size_t)wtIdx * 65536;
    const float* bias = (s < 3) ? (attn_b + s * 256) : (pattn_b + (s - 2) * 256);
    float* outF = wsf + (size_t)s * NND;

    const int tid = threadIdx.x;
    const int wave = tid >> 6, lane = tid & 63;
    const int m0 = blockIdx.x * 64 + wave * 16;
    const int lr = lane & 15;
    const int lk = (lane >> 4) << 3;
    f32x4 acc[4] = {};
    const unsigned short* arow = A  + (size_t)(m0 + lr) * 256 + lk;
    const unsigned short* brow = WT + (size_t)(n0 + lr) * 256 + lk;
    #pragma unroll
    for (int kk = 0; kk < 256; kk += 32) {
        short8 a = *(const short8*)(arow + kk);
        #pragma unroll
        for (int nf = 0; nf < 4; ++nf) {
            short8 b = *(const short8*)(brow + (size_t)nf * 16 * 256 + kk);
            acc[nf] = __builtin_amdgcn_mfma_f32_16x16x32_bf16(a, b, acc[nf], 0, 0, 0);
        }
    }
    const int rbase = m0 + ((lane >> 4) << 2);
    #pragma unroll
    for (int nf = 0; nf < 4; ++nf) {
        int c = n0 + nf * 16 + lr;
        float bc = bias[c];
        #pragma unroll
        for (int jj = 0; jj < 4; ++jj)
            outF[(size_t)(rbase + jj) * 256 + c] = acc[nf][jj] + bc;
    }
}

// ---------------- layernorm: 1 wave per row ----------------
// MODE 0: outF = ln, outB = bf16(ln).  MODE 1: masked write to d_out + flags.
template<int MODE>
__global__ __launch_bounds__(256)
void ln_kernel(const float* __restrict__ in, const float* __restrict__ resid,
               const float* __restrict__ g, const float* __restrict__ b,
               float* __restrict__ outF, unsigned short* __restrict__ outB,
               const int* __restrict__ active, float* __restrict__ flags) {
    const int tid = threadIdx.x;
    const int lane = tid & 63;
    const int row = blockIdx.x * 4 + (tid >> 6);
    const float4 v4 = *(const float4*)(in + (size_t)row * D + lane * 4);
    const float4 r4 = *(const float4*)(resid + (size_t)row * D + lane * 4);
    float v0 = v4.x + r4.x, v1 = v4.y + r4.y, v2 = v4.z + r4.z, v3 = v4.w + r4.w;
    float s1 = v0 + v1 + v2 + v3;
    float s2 = v0 * v0 + v1 * v1 + v2 * v2 + v3 * v3;
    #pragma unroll
    for (int off = 32; off > 0; off >>= 1) {
        s1 += __shfl_xor(s1, off);
        s2 += __shfl_xor(s2, off);
    }
    float mu = s1 * (1.0f / D);
    float var = s2 * (1.0f / D) - mu * mu;
    float rstd = rsqrtf(var + EPS);
    const float4 g4 = *(const float4*)(g + lane * 4);
    const float4 b4 = *(const float4*)(b + lane * 4);
    float o0 = (v0 - mu) * rstd * g4.x + b4.x;
    float o1 = (v1 - mu) * rstd * g4.y + b4.y;
    float o2 = (v2 - mu) * rstd * g4.z + b4.z;
    float o3 = (v3 - mu) * rstd * g4.w + b4.w;
    if (MODE == 0) {
        float4 o; o.x = o0; o.y = o1; o.z = o2; o.w = o3;
        *(float4*)(outF + (size_t)row * D + lane * 4) = o;
        ushort4 u;
        u.x = f2b(o0); u.y = f2b(o1); u.z = f2b(o2); u.w = f2b(o3);
        *(ushort4*)(outB + (size_t)row * D + lane * 4) = u;
    } else {
        bool a = act_at(active, row >> 6, row & 63);
        float4 o;
        o.x = a ? o0 : 0.0f; o.y = a ? o1 : 0.0f;
        o.z = a ? o2 : 0.0f; o.w = a ? o3 : 0.0f;
        *(float4*)(outF + (size_t)row * D + lane * 4) = o;
        if (lane == 0) flags[row] = a ? 1.0f : 0.0f;
    }
}

// ---------------- attn1: masked scores + softmax + PV -> bf16 ----------------
__global__ __launch_bounds__(256)
void attn1_kernel(const int* __restrict__ active,
                  const float* __restrict__ Q1, const float* __restrict__ K1,
                  const float* __restrict__ V1,
                  unsigned short* __restrict__ T1) {
    const int n0 = blockIdx.x * NB;
    const int j = threadIdx.x;
    __shared__ float sc[NB][HEADS][L + 1];
    __shared__ int   nbIdx[NB][L];
    __shared__ unsigned char val1[NB][L];

    if (j < NB * L) {
        int m = j / L, l = j - m * L;
        int n = n0 + m, h = n / GW, w = n % GW;
        int hh = h + l / 5 - 2, ww = w + l % 5 - 2;
        bool ib = (hh >= 0 && hh < GH && ww >= 0 && ww < GW);
        nbIdx[m][l] = ib ? hh * GW + ww : -1;
        val1[m][l] = act_at(active, hh, ww) ? 1 : 0;
    }
    __syncthreads();

    for (int t = j; t < NB * HEADS * L; t += 256) {
        int m = t / (HEADS * L);
        int r = t - m * (HEADS * L);
        int hd = r / L, l = r - hd * L;
        float s = -1e30f;
        if (val1[m][l]) {
            const float4* q = (const float4*)(Q1 + (size_t)(n0 + m) * D + hd * DH);
            const float4* k = (const float4*)(K1 + (size_t)nbIdx[m][l] * D + hd * DH);
            float acc = 0.0f;
            #pragma unroll
            for (int d = 0; d < DH / 4; ++d) {
                float4 qa = q[d], ka = k[d];
                acc = fmaf(qa.x, ka.x, acc); acc = fmaf(qa.y, ka.y, acc);
                acc = fmaf(qa.z, ka.z, acc); acc = fmaf(qa.w, ka.w, acc);
            }
            s = acc * SCALE;
        }
        sc[m][hd][l] = s;
    }
    __syncthreads();
    if (j < NB * HEADS) {
        int m = j / HEADS, hd = j - m * HEADS;
        float mx = -1e30f;
        for (int l = 0; l < L; ++l) mx = fmaxf(mx, sc[m][hd][l]);
        float sum = 0.0f;
        for (int l = 0; l < L; ++l) { float e = expf(sc[m][hd][l] - mx); sc[m][hd][l] = e; sum += e; }
        float inv = 1.0f / sum;
        for (int l = 0; l < L; ++l) sc[m][hd][l] *= inv;
    }
    __syncthreads();
    {
        const int hd = j >> 5;
        float o[NB];
        #pragma unroll
        for (int m = 0; m < NB; ++m) o[m] = 0.0f;
        for (int m = 0; m < NB; ++m)
            for (int l = 0; l < L; ++l)
                if (val1[m][l])
                    o[m] = fmaf(sc[m][hd][l], V1[(size_t)nbIdx[m][l] * D + j], o[m]);
        #pragma unroll
        for (int m = 0; m < NB; ++m)
            T1[(size_t)(n0 + m) * D + j] = f2b(o[m]);
    }
}

// ---------------- attn2: unmasked scores (OOB -> bias K/V) -> bf16 ----------------
__global__ __launch_bounds__(256)
void attn2_kernel(const float* __restrict__ T2, const float* __restrict__ K2,
                  const float* __restrict__ V2, const float* __restrict__ pattn_b,
                  unsigned short* __restrict__ T3) {
    const int n0 = blockIdx.x * NB;
    const int j = threadIdx.x;
    __shared__ float sc[NB][HEADS][L + 1];
    __shared__ int   nbIdx[NB][L];

    if (j < NB * L) {
        int m = j / L, l = j - m * L;
        int n = n0 + m, h = n / GW, w = n % GW;
        int hh = h + l / 5 - 2, ww = w + l % 5 - 2;
        bool ib = (hh >= 0 && hh < GH && ww >= 0 && ww < GW);
        nbIdx[m][l] = ib ? hh * GW + ww : -1;
    }
    __syncthreads();

    for (int t = j; t < NB * HEADS * L; t += 256) {
        int m = t / (HEADS * L);
        int r = t - m * (HEADS * L);
        int hd = r / L, l = r - hd * L;
        int nb = nbIdx[m][l];
        const float4* q = (const float4*)(T2 + (size_t)(n0 + m) * D + hd * DH);
        const float4* k = (nb >= 0) ? (const float4*)(K2 + (size_t)nb * D + hd * DH)
                                    : (const float4*)(pattn_b + D + hd * DH);
        float acc = 0.0f;
        #pragma unroll
        for (int d = 0; d < DH / 4; ++d) {
            float4 qa = q[d], ka = k[d];
            acc = fmaf(qa.x, ka.x, acc); acc = fmaf(qa.y, ka.y, acc);
            acc = fmaf(qa.z, ka.z, acc); acc = fmaf(qa.w, ka.w, acc);
        }
        sc[m][hd][l] = acc * SCALE;
    }
    __syncthreads();
    if (j < NB * HEADS) {
        int m = j / HEADS, hd = j - m * HEADS;
        float mx = -1e30f;
        for (int l = 0; l < L; ++l) mx = fmaxf(mx, sc[m][hd][l]);
        float sum = 0.0f;
        for (int l = 0; l < L; ++l) { float e = expf(sc[m][hd][l] - mx); sc[m][hd][l] = e; sum += e; }
        float inv = 1.0f / sum;
        for (int l = 0; l < L; ++l) sc[m][hd][l] *= inv;
    }
    __syncthreads();
    {
        const int hd = j >> 5;
        float bvv = pattn_b[2 * D + j];
        float o[NB];
        #pragma unroll
        for (int m = 0; m < NB; ++m) o[m] = 0.0f;
        for (int m = 0; m < NB; ++m)
            for (int l = 0; l < L; ++l) {
                int nb = nbIdx[m][l];
                float vv = (nb >= 0) ? V2[(size_t)nb * D + j] : bvv;
                o[m] = fmaf(sc[m][hd][l], vv, o[m]);
            }
        #pragma unroll
        for (int m = 0; m < NB; ++m)
            T3[(size_t)(n0 + m) * D + j] = f2b(o[m]);
    }
}

extern "C" void kernel_launch(void* const* d_in, const int* in_sizes, int n_in,
                              void* d_out, int out_size, void* d_ws, size_t ws_size,
                              hipStream_t stream) {
    const float* x       = (const float*)d_in[0];
    const float* memory  = (const float*)d_in[1];
    const int*   active  = (const int*)d_in[2];
    const float* attn_w  = (const float*)d_in[3];
    const float* attn_b  = (const float*)d_in[4];
    const float* pattn_w = (const float*)d_in[5];
    const float* pattn_b = (const float*)d_in[6];
    const float* ff_w1   = (const float*)d_in[7];
    const float* ff_b1   = (const float*)d_in[8];
    const float* ff_w2   = (const float*)d_in[9];
    const float* ff_b2   = (const float*)d_in[10];
    const float* ln_g    = (const float*)d_in[11];
    const float* ln_b    = (const float*)d_in[12];
    float* out = (float*)d_out;

    float* wsf = (float*)d_ws;
    float* s0 = wsf;              // Q1 -> Spre -> O2 -> F
    float* s1 = wsf + 1 * NND;    // K1 -> S
    float* s2 = wsf + 2 * NND;    // V1 -> S2
    float* s3 = wsf + 3 * NND;    // K2 -> H (bf16, 4096x512)
    float* s4 = wsf + 4 * NND;    // V2
    unsigned short* b0 = (unsigned short*)(wsf + 5 * NND);  // xm -> T1 -> T3
    unsigned short* b1 = b0 + NND;                          // mem -> Sbf -> S2b
    unsigned short* wB = b1 + NND;                          // weights (786432)
    unsigned short* Hb = (unsigned short*)s3;
    float* flags = out + (size_t)NND;

    hipLaunchKernelGGL(prep_kernel, dim3(1024), dim3(256), 0, stream,
                       x, memory, active, attn_w, pattn_w, ff_w1, ff_w2, b0, b1, wB);
    hipLaunchKernelGGL(proj_gemm, dim3(64, 20), dim3(256), 0, stream,
                       b0, b1, wB, attn_b, pattn_b, wsf);
    hipLaunchKernelGGL(attn1_kernel, dim3(NN / NB), dim3(256), 0, stream,
                       active, s0, s1, s2, b0);
    hipLaunchKernelGGL((gemm_kernel<256, 256, 0>), dim3(64, 4), dim3(256), 0, stream,
                       b0, wB + 3 * 65536, attn_b + 3 * D, s0, (unsigned short*)nullptr);
    hipLaunchKernelGGL(ln_kernel<0>, dim3(1024), dim3(256), 0, stream,
                       s0, x, ln_g, ln_b, s1, b1, active, flags);
    hipLaunchKernelGGL((gemm_kernel<256, 256, 0>), dim3(64, 4), dim3(256), 0, stream,
                       b1, wB + 4 * 65536, pattn_b, out, (unsigned short*)nullptr);
    hipLaunchKernelGGL(attn2_kernel, dim3(NN / NB), dim3(256), 0, stream,
                       out, s3, s4, pattn_b, b0);
    hipLaunchKernelGGL((gemm_kernel<256, 256, 0>), dim3(64, 4), dim3(256), 0, stream,
                       b0, wB + 7 * 65536, pattn_b + 3 * D, s0, (unsigned short*)nullptr);
    hipLaunchKernelGGL(ln_kernel<0>, dim3(1024), dim3(256), 0, stream,
                       s0, s1, ln_g + 2 * D, ln_b + 2 * D, s2, b1, active, flags);
    hipLaunchKernelGGL((gemm_kernel<256, 512, 1>), dim3(64, 8), dim3(256), 0, stream,
                       b1, wB + 524288, ff_b1, (float*)nullptr, Hb);
    hipLaunchKernelGGL((gemm_kernel<512, 256, 0>), dim3(64, 4), dim3(256), 0, stream,
                       Hb, wB + 655360, ff_b2, s0, (unsigned short*)nullptr);
    hipLaunchKernelGGL(ln_kernel<1>, dim3(1024), dim3(256), 0, stream,
                       s0, s2, ln_g + D, ln_b + D, out, (unsigned short*)nullptr, active, flags);
}

// Round 6
// 126.012 us; speedup vs baseline: 2.8244x; 1.4632x over previous
//
#include <hip/hip_runtime.h>
#include <math.h>

#define D 256
#define H2 512
#define HEADS 8
#define DH 32
#define L 25
#define GH 64
#define GW 64
#define NN 4096
#define EPS 1e-5f
#define SCALE 0.17677669529663687f  // 1/sqrt(32)
#define NND 1048576                 // NN*D
#define SLOT (NND + 256)            // f32 slot: 4097 rows (extra row = bias for K2/V2)

typedef __attribute__((ext_vector_type(8))) short short8;
typedef __attribute__((ext_vector_type(4))) float f32x4;

__device__ __forceinline__ bool act_at(const int* __restrict__ active, int h, int w) {
    if (h < 0 || h >= GH || w < 0 || w >= GW) return false;
    if (h == 2 && w == 2) return false;   // ap.at[:, center, center].set(False) quirk
    return active[h * GW + w] != 0;
}

__device__ __forceinline__ unsigned short f2b(float f) {
    unsigned u = __float_as_uint(f);
    u += 0x7fffu + ((u >> 16) & 1u);      // RNE
    return (unsigned short)(u >> 16);
}

// ---------------- prep: bf16 conversions + weight transposes + bias rows ----------------
__global__ __launch_bounds__(256)
void prep_kernel(const float* __restrict__ x, const float* __restrict__ mem,
                 const int* __restrict__ active,
                 const float* __restrict__ attn_w, const float* __restrict__ pattn_w,
                 const float* __restrict__ ff_w1, const float* __restrict__ ff_w2,
                 const float* __restrict__ pattn_b,
                 unsigned short* __restrict__ xmB, unsigned short* __restrict__ memB,
                 unsigned short* __restrict__ wB,
                 float* __restrict__ k2bias, float* __restrict__ v2bias) {
    const int TOT = 2884096;
    for (int idx = blockIdx.x * 256 + threadIdx.x; idx < TOT; idx += gridDim.x * 256) {
        if (idx < 1048576) {
            int n = idx >> 8;
            bool a = act_at(active, n >> 6, n & 63);
            xmB[idx] = f2b(a ? x[idx] : 0.0f);
        } else if (idx < 2097152) {
            int t = idx - 1048576;
            memB[t] = f2b(mem[t]);
        } else if (idx < 2621440) {
            int t = idx - 2097152;
            int s = t >> 16, r = t & 65535;
            int n = r >> 8, i = r & 255;
            const float* src = (s < 4) ? (attn_w + s * 65536) : (pattn_w + (s - 4) * 65536);
            wB[t] = f2b(src[i * 256 + n]);             // WT[s][n][i] = W[i][n]
        } else if (idx < 2752512) {
            int t = idx - 2621440;
            int c = t >> 8, i = t & 255;
            wB[524288 + t] = f2b(ff_w1[i * 512 + c]);  // W1T[c][i]
        } else if (idx < 2883584) {
            int t = idx - 2752512;
            int c = t >> 9, k = t & 511;
            wB[655360 + t] = f2b(ff_w2[k * 256 + c]);  // W2T[c][k]
        } else {
            int t = idx - 2883584;
            if (t < 256) k2bias[t] = pattn_b[256 + t];
            else         v2bias[t - 256] = pattn_b[512 + (t - 256)];
        }
    }
}

// ---------------- generic MFMA GEMM: [4096,K]bf16 x WT[N,K]bf16 -> out ----------------
// MODE 0: outF = acc + bias (f32). MODE 1: outB = bf16(relu(acc + bias)).
template<int K, int N, int MODE>
__global__ __launch_bounds__(256)
void gemm_kernel(const unsigned short* __restrict__ A,
                 const unsigned short* __restrict__ WT,
                 const float* __restrict__ bias,
                 float* __restrict__ outF, unsigned short* __restrict__ outB) {
    const int tid = threadIdx.x;
    const int wave = tid >> 6, lane = tid & 63;
    const int m0 = blockIdx.x * 64 + wave * 16;
    const int n0 = blockIdx.y * 64;
    const int lr = lane & 15;
    const int lk = (lane >> 4) << 3;
    f32x4 acc[4] = {};
    const unsigned short* arow = A  + (size_t)(m0 + lr) * K + lk;
    const unsigned short* brow = WT + (size_t)(n0 + lr) * K + lk;
    #pragma unroll 8
    for (int kk = 0; kk < K; kk += 32) {
        short8 a = *(const short8*)(arow + kk);
        #pragma unroll
        for (int nf = 0; nf < 4; ++nf) {
            short8 b = *(const short8*)(brow + (size_t)nf * 16 * K + kk);
            acc[nf] = __builtin_amdgcn_mfma_f32_16x16x32_bf16(a, b, acc[nf], 0, 0, 0);
        }
    }
    const int rbase = m0 + ((lane >> 4) << 2);
    #pragma unroll
    for (int nf = 0; nf < 4; ++nf) {
        int c = n0 + nf * 16 + lr;
        float bc = bias[c];
        #pragma unroll
        for (int jj = 0; jj < 4; ++jj) {
            float v = acc[nf][jj] + bc;
            if (MODE == 0) outF[(size_t)(rbase + jj) * N + c] = v;
            else           outB[(size_t)(rbase + jj) * N + c] = f2b(fmaxf(v, 0.0f));
        }
    }
}

// ---------------- fused GEMM (+bias +residual) + LayerNorm epilogue, N=256 ----------------
// Block: 16 rows x 256 cols (4 waves, one 64-col band each). Grid: 256.
// MODE 0: outF=ln f32, outB=ln bf16.  MODE 1: masked write to out + flags.
template<int K, int MODE>
__global__ __launch_bounds__(256)
void gemmln_kernel(const unsigned short* __restrict__ A,
                   const unsigned short* __restrict__ WT,
                   const float* __restrict__ bias, const float* __restrict__ resid,
                   const float* __restrict__ g, const float* __restrict__ b,
                   float* __restrict__ outF, unsigned short* __restrict__ outB,
                   const int* __restrict__ active, float* __restrict__ flags) {
    const int tid = threadIdx.x;
    const int wave = tid >> 6, lane = tid & 63;
    const int lr = lane & 15;
    const int qi = lane >> 4;            // 0..3
    const int m0 = blockIdx.x * 16;
    const int n0 = wave * 64;
    f32x4 acc[4] = {};
    const unsigned short* arow = A  + (size_t)(m0 + lr) * K + (qi << 3);
    const unsigned short* brow = WT + (size_t)(n0 + lr) * K + (qi << 3);
    #pragma unroll 8
    for (int kk = 0; kk < K; kk += 32) {
        short8 a = *(const short8*)(arow + kk);
        #pragma unroll
        for (int nf = 0; nf < 4; ++nf) {
            short8 bb = *(const short8*)(brow + (size_t)nf * 16 * K + kk);
            acc[nf] = __builtin_amdgcn_mfma_f32_16x16x32_bf16(a, bb, acc[nf], 0, 0, 0);
        }
    }
    // epilogue: +bias +resid, row stats
    float v[4][4];
    float s1[4] = {0.f, 0.f, 0.f, 0.f}, s2[4] = {0.f, 0.f, 0.f, 0.f};
    #pragma unroll
    for (int nf = 0; nf < 4; ++nf) {
        int c = n0 + nf * 16 + lr;
        float bc = bias[c];
        #pragma unroll
        for (int jj = 0; jj < 4; ++jj) {
            int row = m0 + qi * 4 + jj;
            float val = acc[nf][jj] + bc + resid[(size_t)row * D + c];
            v[nf][jj] = val;
            s1[jj] += val;
            s2[jj] += val * val;
        }
    }
    #pragma unroll
    for (int jj = 0; jj < 4; ++jj) {
        #pragma unroll
        for (int off = 1; off < 16; off <<= 1) {
            s1[jj] += __shfl_xor(s1[jj], off);
            s2[jj] += __shfl_xor(s2[jj], off);
        }
    }
    __shared__ float redA[16][4], redB[16][4], stats[16][2];
    if (lr == 0) {
        #pragma unroll
        for (int jj = 0; jj < 4; ++jj) {
            redA[qi * 4 + jj][wave] = s1[jj];
            redB[qi * 4 + jj][wave] = s2[jj];
        }
    }
    __syncthreads();
    if (tid < 16) {
        float a1 = redA[tid][0] + redA[tid][1] + redA[tid][2] + redA[tid][3];
        float a2 = redB[tid][0] + redB[tid][1] + redB[tid][2] + redB[tid][3];
        float mu = a1 * (1.0f / D);
        float var = a2 * (1.0f / D) - mu * mu;
        stats[tid][0] = mu;
        stats[tid][1] = rsqrtf(var + EPS);
    }
    __syncthreads();
    bool arow_act[4];
    if (MODE == 1) {
        #pragma unroll
        for (int jj = 0; jj < 4; ++jj) {
            int row = m0 + qi * 4 + jj;
            arow_act[jj] = act_at(active, row >> 6, row & 63);
        }
    }
    #pragma unroll
    for (int nf = 0; nf < 4; ++nf) {
        int c = n0 + nf * 16 + lr;
        float gg = g[c], bb = b[c];
        #pragma unroll
        for (int jj = 0; jj < 4; ++jj) {
            int ridx = qi * 4 + jj;
            int row = m0 + ridx;
            float o = (v[nf][jj] - stats[ridx][0]) * stats[ridx][1] * gg + bb;
            if (MODE == 0) {
                outF[(size_t)row * D + c] = o;
                outB[(size_t)row * D + c] = f2b(o);
            } else {
                outF[(size_t)row * D + c] = arow_act[jj] ? o : 0.0f;
            }
        }
    }
    if (MODE == 1 && tid < 16) {
        int row = m0 + tid;
        flags[row] = act_at(active, row >> 6, row & 63) ? 1.0f : 0.0f;
    }
}

// ---------------- proj: 5 GEMM streams in one launch ----------------
__global__ __launch_bounds__(256)
void proj_gemm(const unsigned short* __restrict__ xmB,
               const unsigned short* __restrict__ memB,
               const unsigned short* __restrict__ wB,
               const float* __restrict__ attn_b, const float* __restrict__ pattn_b,
               float* __restrict__ wsf) {
    const int s  = blockIdx.y >> 2;       // 0:Q1 1:K1 2:V1 3:K2 4:V2
    const int n0 = (blockIdx.y & 3) * 64;
    const unsigned short* A  = (s < 3) ? xmB : memB;
    const int wtIdx = (s < 3) ? s : (s + 2);            // k2->5, v2->6
    const unsigned short* WT = wB + (size_t)wtIdx * 65536;
    const float* bias = (s < 3) ? (attn_b + s * 256) : (pattn_b + (s - 2) * 256);
    float* outF = wsf + (size_t)s * SLOT;

    const int tid = threadIdx.x;
    const int wave = tid >> 6, lane = tid & 63;
    const int m0 = blockIdx.x * 64 + wave * 16;
    const int lr = lane & 15;
    const int lk = (lane >> 4) << 3;
    f32x4 acc[4] = {};
    const unsigned short* arow = A  + (size_t)(m0 + lr) * 256 + lk;
    const unsigned short* brow = WT + (size_t)(n0 + lr) * 256 + lk;
    #pragma unroll
    for (int kk = 0; kk < 256; kk += 32) {
        short8 a = *(const short8*)(arow + kk);
        #pragma unroll
        for (int nf = 0; nf < 4; ++nf) {
            short8 b = *(const short8*)(brow + (size_t)nf * 16 * 256 + kk);
            acc[nf] = __builtin_amdgcn_mfma_f32_16x16x32_bf16(a, b, acc[nf], 0, 0, 0);
        }
    }
    const int rbase = m0 + ((lane >> 4) << 2);
    #pragma unroll
    for (int nf = 0; nf < 4; ++nf) {
        int c = n0 + nf * 16 + lr;
        float bc = bias[c];
        #pragma unroll
        for (int jj = 0; jj < 4; ++jj)
            outF[(size_t)(rbase + jj) * 256 + c] = acc[nf][jj] + bc;
    }
}

// ---------------- attn1: wave-per-node, masked ----------------
__global__ __launch_bounds__(256)
void attn1_kernel(const int* __restrict__ active,
                  const float* __restrict__ Q, const float* __restrict__ Kb,
                  const float* __restrict__ Vb, unsigned short* __restrict__ T) {
    const int tid = threadIdx.x;
    const int wave = tid >> 6, lane = tid & 63;
    const int n = blockIdx.x * 4 + wave;
    const int h = n >> 6, w = n & 63;
    __shared__ int nbI[4][32];
    __shared__ unsigned char val[4][32];
    __shared__ float wgt[4][8][33];

    if (lane < L) {
        int hh = h + lane / 5 - 2, ww = w + lane % 5 - 2;
        bool ib = ((unsigned)hh < GH) && ((unsigned)ww < GW);
        nbI[wave][lane] = ib ? hh * GW + ww : 0;
        val[wave][lane] = act_at(active, hh, ww) ? 1 : 0;
    }
    __syncthreads();

    const int g8 = lane >> 3;
    float4 q4 = *(const float4*)(Q + (size_t)n * D + lane * 4);
    #pragma unroll 5
    for (int l = 0; l < L; ++l) {
        if (val[wave][l]) {
            int idx = nbI[wave][l];
            float4 k4 = *(const float4*)(Kb + (size_t)idx * D + lane * 4);
            float p = q4.x * k4.x;
            p = fmaf(q4.y, k4.y, p); p = fmaf(q4.z, k4.z, p); p = fmaf(q4.w, k4.w, p);
            p += __shfl_xor(p, 1); p += __shfl_xor(p, 2); p += __shfl_xor(p, 4);
            if ((lane & 7) == 0) wgt[wave][g8][l] = p * SCALE;
        } else {
            if ((lane & 7) == 0) wgt[wave][g8][l] = -1e30f;
        }
    }
    __syncthreads();
    if (lane < HEADS) {
        float mx = -1e30f;
        for (int l = 0; l < L; ++l) mx = fmaxf(mx, wgt[wave][lane][l]);
        float sum = 0.0f;
        for (int l = 0; l < L; ++l) {
            float e = expf(wgt[wave][lane][l] - mx);
            wgt[wave][lane][l] = e;
            sum += e;
        }
        float inv = 1.0f / sum;
        for (int l = 0; l < L; ++l) wgt[wave][lane][l] *= inv;
    }
    __syncthreads();
    float4 o = {0.f, 0.f, 0.f, 0.f};
    #pragma unroll 5
    for (int l = 0; l < L; ++l) {
        if (val[wave][l]) {
            float wv = wgt[wave][g8][l];
            int idx = nbI[wave][l];
            float4 v4 = *(const float4*)(Vb + (size_t)idx * D + lane * 4);
            o.x = fmaf(wv, v4.x, o.x); o.y = fmaf(wv, v4.y, o.y);
            o.z = fmaf(wv, v4.z, o.z); o.w = fmaf(wv, v4.w, o.w);
        }
    }
    ushort4 u;
    u.x = f2b(o.x); u.y = f2b(o.y); u.z = f2b(o.z); u.w = f2b(o.w);
    *(ushort4*)(T + (size_t)n * D + lane * 4) = u;
}

// ---------------- attn2: wave-per-node, unmasked (OOB -> bias row 4096) ----------------
__global__ __launch_bounds__(256)
void attn2_kernel(const float* __restrict__ Q, const float* __restrict__ Kb,
                  const float* __restrict__ Vb, unsigned short* __restrict__ T) {
    const int tid = threadIdx.x;
    const int wave = tid >> 6, lane = tid & 63;
    const int n = blockIdx.x * 4 + wave;
    const int h = n >> 6, w = n & 63;
    __shared__ int nbI[4][32];
    __shared__ float wgt[4][8][33];

    if (lane < L) {
        int hh = h + lane / 5 - 2, ww = w + lane % 5 - 2;
        bool ib = ((unsigned)hh < GH) && ((unsigned)ww < GW);
        nbI[wave][lane] = ib ? hh * GW + ww : NN;     // row NN = bias row
    }
    __syncthreads();

    const int g8 = lane >> 3;
    float4 q4 = *(const float4*)(Q + (size_t)n * D + lane * 4);
    #pragma unroll 5
    for (int l = 0; l < L; ++l) {
        int idx = nbI[wave][l];
        float4 k4 = *(const float4*)(Kb + (size_t)idx * D + lane * 4);
        float p = q4.x * k4.x;
        p = fmaf(q4.y, k4.y, p); p = fmaf(q4.z, k4.z, p); p = fmaf(q4.w, k4.w, p);
        p += __shfl_xor(p, 1); p += __shfl_xor(p, 2); p += __shfl_xor(p, 4);
        if ((lane & 7) == 0) wgt[wave][g8][l] = p * SCALE;
    }
    __syncthreads();
    if (lane < HEADS) {
        float mx = -1e30f;
        for (int l = 0; l < L; ++l) mx = fmaxf(mx, wgt[wave][lane][l]);
        float sum = 0.0f;
        for (int l = 0; l < L; ++l) {
            float e = expf(wgt[wave][lane][l] - mx);
            wgt[wave][lane][l] = e;
            sum += e;
        }
        float inv = 1.0f / sum;
        for (int l = 0; l < L; ++l) wgt[wave][lane][l] *= inv;
    }
    __syncthreads();
    float4 o = {0.f, 0.f, 0.f, 0.f};
    #pragma unroll 5
    for (int l = 0; l < L; ++l) {
        float wv = wgt[wave][g8][l];
        int idx = nbI[wave][l];
        float4 v4 = *(const float4*)(Vb + (size_t)idx * D + lane * 4);
        o.x = fmaf(wv, v4.x, o.x); o.y = fmaf(wv, v4.y, o.y);
        o.z = fmaf(wv, v4.z, o.z); o.w = fmaf(wv, v4.w, o.w);
    }
    ushort4 u;
    u.x = f2b(o.x); u.y = f2b(o.y); u.z = f2b(o.z); u.w = f2b(o.w);
    *(ushort4*)(T + (size_t)n * D + lane * 4) = u;
}

extern "C" void kernel_launch(void* const* d_in, const int* in_sizes, int n_in,
                              void* d_out, int out_size, void* d_ws, size_t ws_size,
                              hipStream_t stream) {
    const float* x       = (const float*)d_in[0];
    const float* memory  = (const float*)d_in[1];
    const int*   active  = (const int*)d_in[2];
    const float* attn_w  = (const float*)d_in[3];
    const float* attn_b  = (const float*)d_in[4];
    const float* pattn_w = (const float*)d_in[5];
    const float* pattn_b = (const float*)d_in[6];
    const float* ff_w1   = (const float*)d_in[7];
    const float* ff_b1   = (const float*)d_in[8];
    const float* ff_w2   = (const float*)d_in[9];
    const float* ff_b2   = (const float*)d_in[10];
    const float* ln_g    = (const float*)d_in[11];
    const float* ln_b    = (const float*)d_in[12];
    float* out = (float*)d_out;

    float* wsf = (float*)d_ws;
    float* s0 = wsf;              // Q1 -> T2
    float* s1 = wsf + 1 * (size_t)SLOT;  // K1 -> S (f32)
    float* s2 = wsf + 2 * (size_t)SLOT;  // V1 -> S2 (f32)
    float* s3 = wsf + 3 * (size_t)SLOT;  // K2x (4097 rows) -> H bf16
    float* s4 = wsf + 4 * (size_t)SLOT;  // V2x (4097 rows)
    unsigned short* b0 = (unsigned short*)(wsf + 5 * (size_t)SLOT); // xm -> T1 -> T3
    unsigned short* b1 = b0 + NND;                                  // mem -> Sbf -> S2bf
    unsigned short* wB = b1 + NND;                                  // weights (786432)
    unsigned short* Hb = (unsigned short*)s3;
    float* flags = out + (size_t)NND;

    hipLaunchKernelGGL(prep_kernel, dim3(1024), dim3(256), 0, stream,
                       x, memory, active, attn_w, pattn_w, ff_w1, ff_w2, pattn_b,
                       b0, b1, wB, s3 + (size_t)NN * D, s4 + (size_t)NN * D);
    hipLaunchKernelGGL(proj_gemm, dim3(64, 20), dim3(256), 0, stream,
                       b0, b1, wB, attn_b, pattn_b, wsf);
    hipLaunchKernelGGL(attn1_kernel, dim3(NN / 4), dim3(256), 0, stream,
                       active, s0, s1, s2, b0);
    hipLaunchKernelGGL((gemmln_kernel<256, 0>), dim3(256), dim3(256), 0, stream,
                       b0, wB + 3 * 65536, attn_b + 3 * D, x, ln_g, ln_b,
                       s1, b1, (const int*)nullptr, (float*)nullptr);
    hipLaunchKernelGGL((gemm_kernel<256, 256, 0>), dim3(64, 4), dim3(256), 0, stream,
                       b1, wB + 4 * 65536, pattn_b, s0, (unsigned short*)nullptr);
    hipLaunchKernelGGL(attn2_kernel, dim3(NN / 4), dim3(256), 0, stream,
                       s0, s3, s4, b0);
    hipLaunchKernelGGL((gemmln_kernel<256, 0>), dim3(256), dim3(256), 0, stream,
                       b0, wB + 7 * 65536, pattn_b + 3 * D, s1, ln_g + 2 * D, ln_b + 2 * D,
                       s2, b1, (const int*)nullptr, (float*)nullptr);
    hipLaunchKernelGGL((gemm_kernel<256, 512, 1>), dim3(64, 8), dim3(256), 0, stream,
                       b1, wB + 524288, ff_b1, (float*)nullptr, Hb);
    hipLaunchKernelGGL((gemmln_kernel<512, 1>), dim3(256), dim3(256), 0, stream,
                       Hb, wB + 655360, ff_b2, s2, ln_g + D, ln_b + D,
                       out, (unsigned short*)nullptr, active, flags);
}

// Round 7
// 114.098 us; speedup vs baseline: 3.1194x; 1.1044x over previous
//
#include <hip/hip_runtime.h>
#include <math.h>

#define D 256
#define H2 512
#define HEADS 8
#define L 25
#define GH 64
#define GW 64
#define NN 4096
#define EPS 1e-5f
#define SCALE 0.17677669529663687f  // 1/sqrt(32)
#define NND 1048576                 // NN*D
#define SLOT (NND + 256)            // f32 slot: 4097 rows (row 4096 = bias for K2/V2)

typedef __attribute__((ext_vector_type(8))) short short8;
typedef __attribute__((ext_vector_type(4))) float f32x4;

__device__ __forceinline__ bool act_at(const int* __restrict__ active, int h, int w) {
    if (h < 0 || h >= GH || w < 0 || w >= GW) return false;
    if (h == 2 && w == 2) return false;   // ap.at[:, center, center].set(False) quirk
    return active[h * GW + w] != 0;
}

__device__ __forceinline__ unsigned short f2b(float f) {
    unsigned u = __float_as_uint(f);
    u += 0x7fffu + ((u >> 16) & 1u);      // RNE
    return (unsigned short)(u >> 16);
}

// ---------------- prep: coalesced bf16 conversions + LDS-tiled weight transposes ----
__global__ __launch_bounds__(256)
void prep_kernel(const float* __restrict__ x, const float* __restrict__ mem,
                 const int* __restrict__ active,
                 const float* __restrict__ attn_w, const float* __restrict__ pattn_w,
                 const float* __restrict__ ff_w1, const float* __restrict__ ff_w2,
                 const float* __restrict__ pattn_b,
                 unsigned short* __restrict__ xmB, unsigned short* __restrict__ memB,
                 unsigned short* __restrict__ wB,
                 float* __restrict__ k2bias, float* __restrict__ v2bias) {
    const int tid = threadIdx.x;
    const int bid = blockIdx.x;
    if (bid < 192) {
        // 64x64 tile transpose, f32 -> bf16:  dst[n][i] = src[i][n]
        __shared__ float tile[64][65];
        const float* src; unsigned short* dst;
        int i0, n0, srcLen, dstLen;
        if (bid < 128) {
            int mat = bid >> 4, t16 = bid & 15;
            i0 = (t16 >> 2) * 64; n0 = (t16 & 3) * 64;
            src = (mat < 4) ? (attn_w + mat * 65536) : (pattn_w + (mat - 4) * 65536);
            dst = wB + mat * 65536;
            srcLen = 256; dstLen = 256;
        } else if (bid < 160) {
            int t = bid - 128;
            i0 = (t >> 3) * 64; n0 = (t & 7) * 64;
            src = ff_w1; dst = wB + 524288;      // W1T: [512][256]
            srcLen = 512; dstLen = 256;
        } else {
            int t = bid - 160;
            i0 = (t >> 2) * 64; n0 = (t & 3) * 64;
            src = ff_w2; dst = wB + 655360;      // W2T: [256][512]
            srcLen = 256; dstLen = 512;
        }
        int c = tid & 63, r4 = tid >> 6;
        for (int rr = 0; rr < 64; rr += 4)
            tile[rr + r4][c] = src[(size_t)(i0 + rr + r4) * srcLen + n0 + c];
        __syncthreads();
        for (int rr = 0; rr < 64; rr += 4) {
            int r = rr + r4;
            dst[(size_t)(n0 + r) * dstLen + i0 + c] = f2b(tile[c][r]);
        }
    } else {
        const int t0 = (bid - 192) * 256 + tid;
        for (int t = t0; t < 524416; t += 512 * 256) {
            if (t < 262144) {
                int n = t >> 6;
                bool a = act_at(active, n >> 6, n & 63);
                float4 v = ((const float4*)x)[t];
                ushort4 u;
                u.x = f2b(a ? v.x : 0.0f); u.y = f2b(a ? v.y : 0.0f);
                u.z = f2b(a ? v.z : 0.0f); u.w = f2b(a ? v.w : 0.0f);
                ((ushort4*)xmB)[t] = u;
            } else if (t < 524288) {
                int tt = t - 262144;
                float4 v = ((const float4*)mem)[tt];
                ushort4 u;
                u.x = f2b(v.x); u.y = f2b(v.y); u.z = f2b(v.z); u.w = f2b(v.w);
                ((ushort4*)memB)[tt] = u;
            } else {
                int tt = t - 524288;   // 0..127: K2/V2 bias rows (row 4096)
                float4 v = ((const float4*)pattn_b)[64 + tt];
                if (tt < 64) ((float4*)k2bias)[tt] = v;
                else         ((float4*)v2bias)[tt - 64] = v;
            }
        }
    }
}

// ---------------- proj: 5 GEMM streams (Q1,K1,V1,K2,V2) ----------------
__global__ __launch_bounds__(256)
void proj_gemm(const unsigned short* __restrict__ xmB,
               const unsigned short* __restrict__ memB,
               const unsigned short* __restrict__ wB,
               const float* __restrict__ attn_b, const float* __restrict__ pattn_b,
               float* __restrict__ wsf) {
    const int s  = blockIdx.y >> 2;       // 0:Q1 1:K1 2:V1 3:K2 4:V2
    const int n0 = (blockIdx.y & 3) * 64;
    const unsigned short* A  = (s < 3) ? xmB : memB;
    const int wtIdx = (s < 3) ? s : (s + 2);            // K2->5, V2->6
    const unsigned short* WT = wB + (size_t)wtIdx * 65536;
    const float* bias = (s < 3) ? (attn_b + s * 256) : (pattn_b + (s - 2) * 256);
    float* outF = wsf + (size_t)s * SLOT;

    const int tid = threadIdx.x;
    const int wave = tid >> 6, lane = tid & 63;
    const int m0 = blockIdx.x * 64 + wave * 16;
    const int lr = lane & 15;
    const int lk = (lane >> 4) << 3;
    f32x4 acc[4] = {};
    const unsigned short* arow = A  + (size_t)(m0 + lr) * 256 + lk;
    const unsigned short* brow = WT + (size_t)(n0 + lr) * 256 + lk;
    #pragma unroll
    for (int kk = 0; kk < 256; kk += 32) {
        short8 a = *(const short8*)(arow + kk);
        #pragma unroll
        for (int nf = 0; nf < 4; ++nf) {
            short8 b = *(const short8*)(brow + (size_t)nf * 16 * 256 + kk);
            acc[nf] = __builtin_amdgcn_mfma_f32_16x16x32_bf16(a, b, acc[nf], 0, 0, 0);
        }
    }
    const int rbase = m0 + ((lane >> 4) << 2);
    #pragma unroll
    for (int nf = 0; nf < 4; ++nf) {
        int c = n0 + nf * 16 + lr;
        float bc = bias[c];
        #pragma unroll
        for (int jj = 0; jj < 4; ++jj)
            outF[(size_t)(rbase + jj) * 256 + c] = acc[nf][jj] + bc;
    }
}

// ---------------- head: attn1 + Wo1+LN0 + Wq2 (16 rows / block) ----------------
__global__ __launch_bounds__(512)
void head_kernel(const int* __restrict__ active, const float* __restrict__ x,
                 const unsigned short* __restrict__ wB,
                 const float* __restrict__ attn_b, const float* __restrict__ pattn_b,
                 const float* __restrict__ ln_g, const float* __restrict__ ln_b,
                 const float* __restrict__ Q1, const float* __restrict__ K1,
                 const float* __restrict__ V1,
                 float* __restrict__ S, float* __restrict__ T2) {
    const int tid = threadIdx.x;
    const int wv = tid >> 6, lane = tid & 63;
    const int lr = lane & 15, qi = lane >> 4;
    const int n0 = blockIdx.x * 16;
    const int g8 = lane >> 3;

    __shared__ unsigned short T1b[16][264];
    __shared__ unsigned short Sb[16][264];
    __shared__ int nbI[16][32];
    __shared__ unsigned char val[16][32];
    __shared__ float wgt[16][8][33];
    __shared__ float redA[16][8], redB[16][8], stats[16][2];

    if (tid < 400) {
        int m = tid / 25, l = tid - m * 25;
        int n = n0 + m, h = n >> 6, w = n & 63;
        int hh = h + l / 5 - 2, ww = w + l % 5 - 2;
        bool ib = ((unsigned)hh < GH) && ((unsigned)ww < GW);
        nbI[m][l] = ib ? hh * GW + ww : 0;
        val[m][l] = act_at(active, hh, ww) ? 1 : 0;
    }
    __syncthreads();

    // ---- attn1 scores (2 nodes / wave) ----
    #pragma unroll
    for (int nn = 0; nn < 2; ++nn) {
        int m = wv * 2 + nn;
        int n = n0 + m;
        float4 q4 = *(const float4*)(Q1 + (size_t)n * D + lane * 4);
        #pragma unroll 5
        for (int l = 0; l < L; ++l) {
            float sv = -1e30f;
            if (val[m][l]) {
                float4 k4 = *(const float4*)(K1 + (size_t)nbI[m][l] * D + lane * 4);
                float p = q4.x * k4.x;
                p = fmaf(q4.y, k4.y, p); p = fmaf(q4.z, k4.z, p); p = fmaf(q4.w, k4.w, p);
                p += __shfl_xor(p, 1); p += __shfl_xor(p, 2); p += __shfl_xor(p, 4);
                sv = p * SCALE;
            }
            if ((lane & 7) == 0) wgt[m][g8][l] = sv;
        }
    }
    __syncthreads();
    if (tid < 128) {
        int m = tid >> 3, hd = tid & 7;
        float mx = -1e30f;
        for (int l = 0; l < L; ++l) mx = fmaxf(mx, wgt[m][hd][l]);
        float sum = 0.0f;
        for (int l = 0; l < L; ++l) { float e = expf(wgt[m][hd][l] - mx); wgt[m][hd][l] = e; sum += e; }
        float inv = 1.0f / sum;
        for (int l = 0; l < L; ++l) wgt[m][hd][l] *= inv;
    }
    __syncthreads();
    // ---- PV -> T1b (LDS bf16) ----
    #pragma unroll
    for (int nn = 0; nn < 2; ++nn) {
        int m = wv * 2 + nn;
        float4 o = {0.f, 0.f, 0.f, 0.f};
        #pragma unroll 5
        for (int l = 0; l < L; ++l) {
            if (val[m][l]) {
                float wt = wgt[m][g8][l];
                float4 v4 = *(const float4*)(V1 + (size_t)nbI[m][l] * D + lane * 4);
                o.x = fmaf(wt, v4.x, o.x); o.y = fmaf(wt, v4.y, o.y);
                o.z = fmaf(wt, v4.z, o.z); o.w = fmaf(wt, v4.w, o.w);
            }
        }
        ushort4 u; u.x = f2b(o.x); u.y = f2b(o.y); u.z = f2b(o.z); u.w = f2b(o.w);
        *(ushort4*)&T1b[m][lane * 4] = u;
    }
    __syncthreads();

    // ---- Wo1 (A from LDS) + bias + resid(x) + LN0 -> S (f32 global) + Sb (LDS) ----
    {
        const unsigned short* Wo1T = wB + 3 * 65536;
        f32x4 acc[2] = {};
        #pragma unroll
        for (int kk = 0; kk < 256; kk += 32) {
            short8 a = *(const short8*)&T1b[lr][qi * 8 + kk];
            #pragma unroll
            for (int nf = 0; nf < 2; ++nf) {
                short8 b = *(const short8*)(Wo1T + (size_t)(wv * 32 + nf * 16 + lr) * 256 + qi * 8 + kk);
                acc[nf] = __builtin_amdgcn_mfma_f32_16x16x32_bf16(a, b, acc[nf], 0, 0, 0);
            }
        }
        float v[2][4], s1[4] = {0.f,0.f,0.f,0.f}, s2[4] = {0.f,0.f,0.f,0.f};
        #pragma unroll
        for (int nf = 0; nf < 2; ++nf) {
            int c = wv * 32 + nf * 16 + lr;
            float bc = attn_b[768 + c];
            #pragma unroll
            for (int jj = 0; jj < 4; ++jj) {
                int row = n0 + qi * 4 + jj;
                float vv = acc[nf][jj] + bc + x[(size_t)row * D + c];
                v[nf][jj] = vv; s1[jj] += vv; s2[jj] += vv * vv;
            }
        }
        #pragma unroll
        for (int jj = 0; jj < 4; ++jj) {
            #pragma unroll
            for (int off = 1; off < 16; off <<= 1) {
                s1[jj] += __shfl_xor(s1[jj], off);
                s2[jj] += __shfl_xor(s2[jj], off);
            }
        }
        if (lr == 0) {
            #pragma unroll
            for (int jj = 0; jj < 4; ++jj) { redA[qi*4+jj][wv] = s1[jj]; redB[qi*4+jj][wv] = s2[jj]; }
        }
        __syncthreads();
        if (tid < 16) {
            float a1 = 0.f, a2 = 0.f;
            #pragma unroll
            for (int q = 0; q < 8; ++q) { a1 += redA[tid][q]; a2 += redB[tid][q]; }
            float mu = a1 * (1.0f / D);
            float var = a2 * (1.0f / D) - mu * mu;
            stats[tid][0] = mu; stats[tid][1] = rsqrtf(var + EPS);
        }
        __syncthreads();
        #pragma unroll
        for (int nf = 0; nf < 2; ++nf) {
            int c = wv * 32 + nf * 16 + lr;
            float gg = ln_g[c], bb = ln_b[c];
            #pragma unroll
            for (int jj = 0; jj < 4; ++jj) {
                int ridx = qi * 4 + jj;
                float o = (v[nf][jj] - stats[ridx][0]) * stats[ridx][1] * gg + bb;
                S[(size_t)(n0 + ridx) * D + c] = o;
                Sb[ridx][c] = f2b(o);
            }
        }
    }
    __syncthreads();

    // ---- Wq2 -> T2 (f32 global) ----
    {
        const unsigned short* Wq2T = wB + 4 * 65536;
        f32x4 acc[2] = {};
        #pragma unroll
        for (int kk = 0; kk < 256; kk += 32) {
            short8 a = *(const short8*)&Sb[lr][qi * 8 + kk];
            #pragma unroll
            for (int nf = 0; nf < 2; ++nf) {
                short8 b = *(const short8*)(Wq2T + (size_t)(wv * 32 + nf * 16 + lr) * 256 + qi * 8 + kk);
                acc[nf] = __builtin_amdgcn_mfma_f32_16x16x32_bf16(a, b, acc[nf], 0, 0, 0);
            }
        }
        #pragma unroll
        for (int nf = 0; nf < 2; ++nf) {
            int c = wv * 32 + nf * 16 + lr;
            float bc = pattn_b[c];
            #pragma unroll
            for (int jj = 0; jj < 4; ++jj)
                T2[(size_t)(n0 + qi * 4 + jj) * D + c] = acc[nf][jj] + bc;
        }
    }
}

// ---------------- tail: attn2 + Wo2+LN2 + FF1 + FF2+LN1+mask ----------------
__global__ __launch_bounds__(512)
void tail_kernel(const int* __restrict__ active,
                 const unsigned short* __restrict__ wB,
                 const float* __restrict__ pattn_b, const float* __restrict__ ff_b1,
                 const float* __restrict__ ff_b2,
                 const float* __restrict__ ln_g, const float* __restrict__ ln_b,
                 const float* __restrict__ K2x, const float* __restrict__ V2x,
                 const float* __restrict__ S, const float* __restrict__ T2,
                 float* __restrict__ out) {
    const int tid = threadIdx.x;
    const int wv = tid >> 6, lane = tid & 63;
    const int lr = lane & 15, qi = lane >> 4;
    const int n0 = blockIdx.x * 16;
    const int g8 = lane >> 3;

    __shared__ unsigned short T3b[16][264];
    __shared__ float S2f[16][260];
    __shared__ unsigned short S2b[16][264];
    __shared__ float redA[16][8], redB[16][8], stats[16][2];
    __shared__ __align__(16) char smU[18944];     // attn scratch, aliased with Hb
    int   (*nbI)[32]    = (int(*)[32])smU;        // 2048 B
    float (*wgt)[8][33] = (float(*)[8][33])(smU + 2048);  // 16896 B
    unsigned short (*Hb)[520] = (unsigned short(*)[520])smU; // 16640 B (after attn)

    if (tid < 400) {
        int m = tid / 25, l = tid - m * 25;
        int n = n0 + m, h = n >> 6, w = n & 63;
        int hh = h + l / 5 - 2, ww = w + l % 5 - 2;
        bool ib = ((unsigned)hh < GH) && ((unsigned)ww < GW);
        nbI[m][l] = ib ? hh * GW + ww : NN;       // row NN = bias row
    }
    __syncthreads();

    // ---- attn2 scores (unmasked) ----
    #pragma unroll
    for (int nn = 0; nn < 2; ++nn) {
        int m = wv * 2 + nn;
        int n = n0 + m;
        float4 q4 = *(const float4*)(T2 + (size_t)n * D + lane * 4);
        #pragma unroll 5
        for (int l = 0; l < L; ++l) {
            float4 k4 = *(const float4*)(K2x + (size_t)nbI[m][l] * D + lane * 4);
            float p = q4.x * k4.x;
            p = fmaf(q4.y, k4.y, p); p = fmaf(q4.z, k4.z, p); p = fmaf(q4.w, k4.w, p);
            p += __shfl_xor(p, 1); p += __shfl_xor(p, 2); p += __shfl_xor(p, 4);
            if ((lane & 7) == 0) wgt[m][g8][l] = p * SCALE;
        }
    }
    __syncthreads();
    if (tid < 128) {
        int m = tid >> 3, hd = tid & 7;
        float mx = -1e30f;
        for (int l = 0; l < L; ++l) mx = fmaxf(mx, wgt[m][hd][l]);
        float sum = 0.0f;
        for (int l = 0; l < L; ++l) { float e = expf(wgt[m][hd][l] - mx); wgt[m][hd][l] = e; sum += e; }
        float inv = 1.0f / sum;
        for (int l = 0; l < L; ++l) wgt[m][hd][l] *= inv;
    }
    __syncthreads();
    #pragma unroll
    for (int nn = 0; nn < 2; ++nn) {
        int m = wv * 2 + nn;
        float4 o = {0.f, 0.f, 0.f, 0.f};
        #pragma unroll 5
        for (int l = 0; l < L; ++l) {
            float wt = wgt[m][g8][l];
            float4 v4 = *(const float4*)(V2x + (size_t)nbI[m][l] * D + lane * 4);
            o.x = fmaf(wt, v4.x, o.x); o.y = fmaf(wt, v4.y, o.y);
            o.z = fmaf(wt, v4.z, o.z); o.w = fmaf(wt, v4.w, o.w);
        }
        ushort4 u; u.x = f2b(o.x); u.y = f2b(o.y); u.z = f2b(o.z); u.w = f2b(o.w);
        *(ushort4*)&T3b[m][lane * 4] = u;
    }
    __syncthreads();

    // ---- Wo2 + bias + resid(S) + LN2 -> S2f/S2b (LDS only) ----
    {
        const unsigned short* Wo2T = wB + 7 * 65536;
        f32x4 acc[2] = {};
        #pragma unroll
        for (int kk = 0; kk < 256; kk += 32) {
            short8 a = *(const short8*)&T3b[lr][qi * 8 + kk];
            #pragma unroll
            for (int nf = 0; nf < 2; ++nf) {
                short8 b = *(const short8*)(Wo2T + (size_t)(wv * 32 + nf * 16 + lr) * 256 + qi * 8 + kk);
                acc[nf] = __builtin_amdgcn_mfma_f32_16x16x32_bf16(a, b, acc[nf], 0, 0, 0);
            }
        }
        float v[2][4], s1[4] = {0.f,0.f,0.f,0.f}, s2[4] = {0.f,0.f,0.f,0.f};
        #pragma unroll
        for (int nf = 0; nf < 2; ++nf) {
            int c = wv * 32 + nf * 16 + lr;
            float bc = pattn_b[768 + c];
            #pragma unroll
            for (int jj = 0; jj < 4; ++jj) {
                int row = n0 + qi * 4 + jj;
                float vv = acc[nf][jj] + bc + S[(size_t)row * D + c];
                v[nf][jj] = vv; s1[jj] += vv; s2[jj] += vv * vv;
            }
        }
        #pragma unroll
        for (int jj = 0; jj < 4; ++jj) {
            #pragma unroll
            for (int off = 1; off < 16; off <<= 1) {
                s1[jj] += __shfl_xor(s1[jj], off);
                s2[jj] += __shfl_xor(s2[jj], off);
            }
        }
        if (lr == 0) {
            #pragma unroll
            for (int jj = 0; jj < 4; ++jj) { redA[qi*4+jj][wv] = s1[jj]; redB[qi*4+jj][wv] = s2[jj]; }
        }
        __syncthreads();
        if (tid < 16) {
            float a1 = 0.f, a2 = 0.f;
            #pragma unroll
            for (int q = 0; q < 8; ++q) { a1 += redA[tid][q]; a2 += redB[tid][q]; }
            float mu = a1 * (1.0f / D);
            float var = a2 * (1.0f / D) - mu * mu;
            stats[tid][0] = mu; stats[tid][1] = rsqrtf(var + EPS);
        }
        __syncthreads();
        #pragma unroll
        for (int nf = 0; nf < 2; ++nf) {
            int c = wv * 32 + nf * 16 + lr;
            float gg = ln_g[512 + c], bb = ln_b[512 + c];
            #pragma unroll
            for (int jj = 0; jj < 4; ++jj) {
                int ridx = qi * 4 + jj;
                float o = (v[nf][jj] - stats[ridx][0]) * stats[ridx][1] * gg + bb;
                S2f[ridx][c] = o;
                S2b[ridx][c] = f2b(o);
            }
        }
    }
    __syncthreads();   // S2 ready; attn scratch dead -> Hb region usable

    // ---- FF1: S2 @ W1 + b1, relu -> Hb (LDS bf16, 16x512) ----
    {
        const unsigned short* W1T = wB + 524288;
        f32x4 acc[4] = {};
        #pragma unroll
        for (int kk = 0; kk < 256; kk += 32) {
            short8 a = *(const short8*)&S2b[lr][qi * 8 + kk];
            #pragma unroll
            for (int nf = 0; nf < 4; ++nf) {
                short8 b = *(const short8*)(W1T + (size_t)(wv * 64 + nf * 16 + lr) * 256 + qi * 8 + kk);
                acc[nf] = __builtin_amdgcn_mfma_f32_16x16x32_bf16(a, b, acc[nf], 0, 0, 0);
            }
        }
        #pragma unroll
        for (int nf = 0; nf < 4; ++nf) {
            int c = wv * 64 + nf * 16 + lr;
            float bc = ff_b1[c];
            #pragma unroll
            for (int jj = 0; jj < 4; ++jj)
                Hb[qi * 4 + jj][c] = f2b(fmaxf(acc[nf][jj] + bc, 0.0f));
        }
    }
    __syncthreads();

    // ---- FF2 (K=512) + bias + resid(S2f) + LN1 + mask -> out ----
    {
        const unsigned short* W2T = wB + 655360;
        f32x4 acc[2] = {};
        #pragma unroll
        for (int kk = 0; kk < 512; kk += 32) {
            short8 a = *(const short8*)&Hb[lr][qi * 8 + kk];
            #pragma unroll
            for (int nf = 0; nf < 2; ++nf) {
                short8 b = *(const short8*)(W2T + (size_t)(wv * 32 + nf * 16 + lr) * 512 + qi * 8 + kk);
                acc[nf] = __builtin_amdgcn_mfma_f32_16x16x32_bf16(a, b, acc[nf], 0, 0, 0);
            }
        }
        float v[2][4], s1[4] = {0.f,0.f,0.f,0.f}, s2[4] = {0.f,0.f,0.f,0.f};
        #pragma unroll
        for (int nf = 0; nf < 2; ++nf) {
            int c = wv * 32 + nf * 16 + lr;
            float bc = ff_b2[c];
            #pragma unroll
            for (int jj = 0; jj < 4; ++jj) {
                int ridx = qi * 4 + jj;
                float vv = acc[nf][jj] + bc + S2f[ridx][c];
                v[nf][jj] = vv; s1[jj] += vv; s2[jj] += vv * vv;
            }
        }
        #pragma unroll
        for (int jj = 0; jj < 4; ++jj) {
            #pragma unroll
            for (int off = 1; off < 16; off <<= 1) {
                s1[jj] += __shfl_xor(s1[jj], off);
                s2[jj] += __shfl_xor(s2[jj], off);
            }
        }
        if (lr == 0) {
            #pragma unroll
            for (int jj = 0; jj < 4; ++jj) { redA[qi*4+jj][wv] = s1[jj]; redB[qi*4+jj][wv] = s2[jj]; }
        }
        __syncthreads();
        if (tid < 16) {
            float a1 = 0.f, a2 = 0.f;
            #pragma unroll
            for (int q = 0; q < 8; ++q) { a1 += redA[tid][q]; a2 += redB[tid][q]; }
            float mu = a1 * (1.0f / D);
            float var = a2 * (1.0f / D) - mu * mu;
            stats[tid][0] = mu; stats[tid][1] = rsqrtf(var + EPS);
        }
        __syncthreads();
        bool arow_act[4];
        #pragma unroll
        for (int jj = 0; jj < 4; ++jj) {
            int row = n0 + qi * 4 + jj;
            arow_act[jj] = act_at(active, row >> 6, row & 63);
        }
        #pragma unroll
        for (int nf = 0; nf < 2; ++nf) {
            int c = wv * 32 + nf * 16 + lr;
            float gg = ln_g[256 + c], bb = ln_b[256 + c];
            #pragma unroll
            for (int jj = 0; jj < 4; ++jj) {
                int ridx = qi * 4 + jj;
                float o = (v[nf][jj] - stats[ridx][0]) * stats[ridx][1] * gg + bb;
                out[(size_t)(n0 + ridx) * D + c] = arow_act[jj] ? o : 0.0f;
            }
        }
        if (tid < 16) {
            int row = n0 + tid;
            out[(size_t)NND + row] = act_at(active, row >> 6, row & 63) ? 1.0f : 0.0f;
        }
    }
}

extern "C" void kernel_launch(void* const* d_in, const int* in_sizes, int n_in,
                              void* d_out, int out_size, void* d_ws, size_t ws_size,
                              hipStream_t stream) {
    const float* x       = (const float*)d_in[0];
    const float* memory  = (const float*)d_in[1];
    const int*   active  = (const int*)d_in[2];
    const float* attn_w  = (const float*)d_in[3];
    const float* attn_b  = (const float*)d_in[4];
    const float* pattn_w = (const float*)d_in[5];
    const float* pattn_b = (const float*)d_in[6];
    const float* ff_w1   = (const float*)d_in[7];
    const float* ff_b1   = (const float*)d_in[8];
    const float* ff_w2   = (const float*)d_in[9];
    const float* ff_b2   = (const float*)d_in[10];
    const float* ln_g    = (const float*)d_in[11];
    const float* ln_b    = (const float*)d_in[12];
    float* out = (float*)d_out;

    float* wsf = (float*)d_ws;
    float* Q1  = wsf + 0 * (size_t)SLOT;
    float* K1  = wsf + 1 * (size_t)SLOT;
    float* V1  = wsf + 2 * (size_t)SLOT;
    float* K2x = wsf + 3 * (size_t)SLOT;   // 4097 rows (row 4096 = bias)
    float* V2x = wsf + 4 * (size_t)SLOT;
    float* Sst = wsf + 5 * (size_t)SLOT;
    float* T2  = wsf + 6 * (size_t)SLOT;
    unsigned short* b0 = (unsigned short*)(wsf + 7 * (size_t)SLOT); // xmB
    unsigned short* b1 = b0 + NND;                                  // memB
    unsigned short* wB = b1 + NND;                                  // 786432 shorts

    hipLaunchKernelGGL(prep_kernel, dim3(704), dim3(256), 0, stream,
                       x, memory, active, attn_w, pattn_w, ff_w1, ff_w2, pattn_b,
                       b0, b1, wB, K2x + (size_t)NND, V2x + (size_t)NND);
    hipLaunchKernelGGL(proj_gemm, dim3(64, 20), dim3(256), 0, stream,
                       b0, b1, wB, attn_b, pattn_b, wsf);
    hipLaunchKernelGGL(head_kernel, dim3(256), dim3(512), 0, stream,
                       active, x, wB, attn_b, pattn_b, ln_g, ln_b,
                       Q1, K1, V1, Sst, T2);
    hipLaunchKernelGGL(tail_kernel, dim3(256), dim3(512), 0, stream,
                       active, wB, pattn_b, ff_b1, ff_b2, ln_g, ln_b,
                       K2x, V2x, Sst, T2, out);
}

// Round 8
// 93.239 us; speedup vs baseline: 3.8172x; 1.2237x over previous
//
#include <hip/hip_runtime.h>
#include <math.h>

#define D 256
#define H2 512
#define HEADS 8
#define L 25
#define GH 64
#define GW 64
#define NN 4096
#define EPS 1e-5f
#define SCALE 0.17677669529663687f  // 1/sqrt(32)
#define NND 1048576                 // NN*D

typedef __attribute__((ext_vector_type(8))) short short8;
typedef __attribute__((ext_vector_type(4))) float f32x4;

__device__ __forceinline__ bool act_at(const int* __restrict__ active, int h, int w) {
    if (h < 0 || h >= GH || w < 0 || w >= GW) return false;
    if (h == 2 && w == 2) return false;   // ap.at[:, center, center].set(False) quirk
    return active[h * GW + w] != 0;
}

__device__ __forceinline__ unsigned short f2b(float f) {
    unsigned u = __float_as_uint(f);
    u += 0x7fffu + ((u >> 16) & 1u);      // RNE
    return (unsigned short)(u >> 16);
}
__device__ __forceinline__ float b2f(short v) {
    return __uint_as_float(((unsigned)(unsigned short)v) << 16);
}

// ---------------- prep: bf16 conversions + LDS-tiled weight transposes ----------------
__global__ __launch_bounds__(256)
void prep_kernel(const float* __restrict__ x, const float* __restrict__ mem,
                 const int* __restrict__ active,
                 const float* __restrict__ attn_w, const float* __restrict__ pattn_w,
                 const float* __restrict__ ff_w1, const float* __restrict__ ff_w2,
                 const float* __restrict__ pattn_b,
                 unsigned short* __restrict__ xmB, unsigned short* __restrict__ memB,
                 unsigned short* __restrict__ wB,
                 unsigned short* __restrict__ k2bias, unsigned short* __restrict__ v2bias) {
    const int tid = threadIdx.x;
    const int bid = blockIdx.x;
    if (bid < 192) {
        __shared__ float tile[64][65];
        const float* src; unsigned short* dst;
        int i0, n0, srcLen, dstLen;
        if (bid < 128) {
            int mat = bid >> 4, t16 = bid & 15;
            i0 = (t16 >> 2) * 64; n0 = (t16 & 3) * 64;
            src = (mat < 4) ? (attn_w + mat * 65536) : (pattn_w + (mat - 4) * 65536);
            dst = wB + mat * 65536;
            srcLen = 256; dstLen = 256;
        } else if (bid < 160) {
            int t = bid - 128;
            i0 = (t >> 3) * 64; n0 = (t & 7) * 64;
            src = ff_w1; dst = wB + 524288;      // W1T: [512][256]
            srcLen = 512; dstLen = 256;
        } else {
            int t = bid - 160;
            i0 = (t >> 2) * 64; n0 = (t & 3) * 64;
            src = ff_w2; dst = wB + 655360;      // W2T: [256][512]
            srcLen = 256; dstLen = 512;
        }
        int c = tid & 63, r4 = tid >> 6;
        for (int rr = 0; rr < 64; rr += 4)
            tile[rr + r4][c] = src[(size_t)(i0 + rr + r4) * srcLen + n0 + c];
        __syncthreads();
        for (int rr = 0; rr < 64; rr += 4) {
            int r = rr + r4;
            dst[(size_t)(n0 + r) * dstLen + i0 + c] = f2b(tile[c][r]);
        }
    } else {
        const int t0 = (bid - 192) * 256 + tid;
        for (int t = t0; t < 524800; t += 512 * 256) {
            if (t < 262144) {
                int n = t >> 6;
                bool a = act_at(active, n >> 6, n & 63);
                float4 v = ((const float4*)x)[t];
                ushort4 u;
                u.x = f2b(a ? v.x : 0.0f); u.y = f2b(a ? v.y : 0.0f);
                u.z = f2b(a ? v.z : 0.0f); u.w = f2b(a ? v.w : 0.0f);
                ((ushort4*)xmB)[t] = u;
            } else if (t < 524288) {
                int tt = t - 262144;
                float4 v = ((const float4*)mem)[tt];
                ushort4 u;
                u.x = f2b(v.x); u.y = f2b(v.y); u.z = f2b(v.z); u.w = f2b(v.w);
                ((ushort4*)memB)[tt] = u;
            } else {
                int tt = t - 524288;   // 512 scalars: K2/V2 bias rows (row 4096, bf16)
                if (tt < 256) k2bias[tt] = f2b(pattn_b[256 + tt]);
                else          v2bias[tt - 256] = f2b(pattn_b[512 + (tt - 256)]);
            }
        }
    }
}

// ---------------- proj: 5 GEMM streams -> bf16 outputs ----------------
__global__ __launch_bounds__(256)
void proj_gemm(const unsigned short* __restrict__ xmB,
               const unsigned short* __restrict__ memB,
               const unsigned short* __restrict__ wB,
               const float* __restrict__ attn_b, const float* __restrict__ pattn_b,
               unsigned short* __restrict__ q1b, unsigned short* __restrict__ k1b,
               unsigned short* __restrict__ v1b, unsigned short* __restrict__ k2b,
               unsigned short* __restrict__ v2b) {
    const int s  = blockIdx.y >> 2;       // 0:Q1 1:K1 2:V1 3:K2 4:V2
    const int n0 = (blockIdx.y & 3) * 64;
    const unsigned short* A  = (s < 3) ? xmB : memB;
    const int wtIdx = (s < 3) ? s : (s + 2);            // K2->5, V2->6
    const unsigned short* WT = wB + (size_t)wtIdx * 65536;
    const float* bias = (s < 3) ? (attn_b + s * 256) : (pattn_b + (s - 2) * 256);
    unsigned short* outB;
    switch (s) { case 0: outB = q1b; break; case 1: outB = k1b; break;
                 case 2: outB = v1b; break; case 3: outB = k2b; break;
                 default: outB = v2b; }

    const int tid = threadIdx.x;
    const int wave = tid >> 6, lane = tid & 63;
    const int m0 = blockIdx.x * 64 + wave * 16;
    const int lr = lane & 15;
    const int lk = (lane >> 4) << 3;
    f32x4 acc[4] = {};
    const unsigned short* arow = A  + (size_t)(m0 + lr) * 256 + lk;
    const unsigned short* brow = WT + (size_t)(n0 + lr) * 256 + lk;
    #pragma unroll
    for (int kk = 0; kk < 256; kk += 32) {
        short8 a = *(const short8*)(arow + kk);
        #pragma unroll
        for (int nf = 0; nf < 4; ++nf) {
            short8 b = *(const short8*)(brow + (size_t)nf * 16 * 256 + kk);
            acc[nf] = __builtin_amdgcn_mfma_f32_16x16x32_bf16(a, b, acc[nf], 0, 0, 0);
        }
    }
    const int rbase = m0 + ((lane >> 4) << 2);
    #pragma unroll
    for (int nf = 0; nf < 4; ++nf) {
        int c = n0 + nf * 16 + lr;
        float bc = bias[c];
        #pragma unroll
        for (int jj = 0; jj < 4; ++jj)
            outB[(size_t)(rbase + jj) * 256 + c] = f2b(acc[nf][jj] + bc);
    }
}

// ---------------- shared LDS layout for head/tail ----------------
// [0, 51200):       kvU union (100 rows x 256 bf16)  -> phase B scratch
// [51200, 51328):   actU (head only)
// [51328, 64128):   wgt [16][8][25] f32
// [64128, 65152):   redA/redB
// [65152, 65280):   stats
#define KV_OFF   0
#define ACT_OFF  51200
#define WGT_OFF  51328
#define REDA_OFF 64128
#define REDB_OFF 64640
#define STAT_OFF 65152
#define SMEM_SZ  65280
// phase B aliases (into [0,51200)):
#define T1B_OFF  0          // [16][264] bf16 = 8448
#define SB_OFF   8448       // [16][264] bf16 = 8448
#define S2F_OFF  8448       // tail: [16][260] f32 = 16640
#define S2B_OFF  25088      // tail: [16][264] bf16 = 8448
#define HB_OFF   33536      // tail: [16][520] bf16 = 16640

__device__ __forceinline__ void load_union(const unsigned short* __restrict__ base,
                                           int h, int w0, int fallback,
                                           unsigned short (*kvU)[256], int tid) {
    for (int c = tid; c < 3200; c += 512) {
        int u = c >> 5, part = c & 31;
        int r = u / 20;
        int hh = h - 2 + r, ww = w0 - 2 + (u - r * 20);
        bool ib = ((unsigned)hh < GH) && ((unsigned)ww < GW);
        int row = ib ? ((hh << 6) | ww) : fallback;
        *(uint4*)&kvU[u][part * 8] = *(const uint4*)(base + (size_t)row * 256 + part * 8);
    }
}

// ---------------- head: attn1(union) + Wo1+LN0 + Wq2 ----------------
__global__ __launch_bounds__(512)
void head_kernel(const int* __restrict__ active, const float* __restrict__ x,
                 const unsigned short* __restrict__ wB,
                 const float* __restrict__ attn_b, const float* __restrict__ pattn_b,
                 const float* __restrict__ ln_g, const float* __restrict__ ln_b,
                 const unsigned short* __restrict__ q1b,
                 const unsigned short* __restrict__ k1b,
                 const unsigned short* __restrict__ v1b,
                 float* __restrict__ S, unsigned short* __restrict__ T2b) {
    const int tid = threadIdx.x;
    const int wv = tid >> 6, lane = tid & 63;
    const int lr = lane & 15, qi = lane >> 4;
    const int n0 = blockIdx.x * 16;
    const int h = n0 >> 6, w0 = n0 & 63;

    __shared__ __align__(16) char smem[SMEM_SZ];
    unsigned short (*kvU)[256] = (unsigned short(*)[256])(smem + KV_OFF);
    unsigned char* actU        = (unsigned char*)(smem + ACT_OFF);
    float (*wgt)[8][25]        = (float(*)[8][25])(smem + WGT_OFF);
    float (*redA)[8]           = (float(*)[8])(smem + REDA_OFF);
    float (*redB)[8]           = (float(*)[8])(smem + REDB_OFF);
    float (*stats)[2]          = (float(*)[2])(smem + STAT_OFF);
    unsigned short (*T1b)[264] = (unsigned short(*)[264])(smem + T1B_OFF);
    unsigned short (*Sb)[264]  = (unsigned short(*)[264])(smem + SB_OFF);

    if (tid < 100) {
        int r = tid / 20;
        int hh = h - 2 + r, ww = w0 - 2 + (tid - r * 20);
        actU[tid] = act_at(active, hh, ww) ? 1 : 0;
    }
    load_union(k1b, h, w0, 0, kvU, tid);
    __syncthreads();

    // ---- scores: half-wave per node ----
    const int half = lane >> 5, lam = lane & 31;
    const int m = wv * 2 + half;
    float q[8];
    {
        short8 qv = *(const short8*)(q1b + (size_t)(n0 + m) * 256 + lam * 8);
        #pragma unroll
        for (int j = 0; j < 8; ++j) q[j] = b2f(qv[j]);
    }
    #pragma unroll 5
    for (int l = 0; l < L; ++l) {
        int u = (l / 5) * 20 + m + (l % 5);
        short8 kv = *(const short8*)&kvU[u][lam * 8];
        float p = q[0] * b2f(kv[0]);
        #pragma unroll
        for (int j = 1; j < 8; ++j) p = fmaf(q[j], b2f(kv[j]), p);
        p += __shfl_xor(p, 1); p += __shfl_xor(p, 2);
        float sv = actU[u] ? p * SCALE : -1e30f;
        if ((lam & 3) == 0) wgt[m][lam >> 2][l] = sv;
    }
    __syncthreads();
    if (tid < 128) {
        int mm = tid >> 3, hd = tid & 7;
        float mx = -1e30f;
        for (int l = 0; l < L; ++l) mx = fmaxf(mx, wgt[mm][hd][l]);
        float sum = 0.0f;
        for (int l = 0; l < L; ++l) { float e = expf(wgt[mm][hd][l] - mx); wgt[mm][hd][l] = e; sum += e; }
        float inv = 1.0f / sum;
        for (int l = 0; l < L; ++l) wgt[mm][hd][l] *= inv;
    }
    __syncthreads();
    load_union(v1b, h, w0, 0, kvU, tid);
    __syncthreads();
    // ---- PV ----
    float o[8] = {0.f,0.f,0.f,0.f,0.f,0.f,0.f,0.f};
    #pragma unroll 5
    for (int l = 0; l < L; ++l) {
        int u = (l / 5) * 20 + m + (l % 5);
        if (actU[u]) {
            float wt = wgt[m][lam >> 2][l];
            short8 v8 = *(const short8*)&kvU[u][lam * 8];
            #pragma unroll
            for (int j = 0; j < 8; ++j) o[j] = fmaf(wt, b2f(v8[j]), o[j]);
        }
    }
    __syncthreads();   // union reads done
    {
        unsigned short u8[8];
        #pragma unroll
        for (int j = 0; j < 8; ++j) u8[j] = f2b(o[j]);
        *(uint4*)&T1b[m][lam * 8] = *(uint4*)u8;
    }
    __syncthreads();

    // ---- Wo1 + bias + resid(x) + LN0 -> S (f32) + Sb ----
    {
        const unsigned short* Wo1T = wB + 3 * 65536;
        f32x4 acc[2] = {};
        #pragma unroll
        for (int kk = 0; kk < 256; kk += 32) {
            short8 a = *(const short8*)&T1b[lr][qi * 8 + kk];
            #pragma unroll
            for (int nf = 0; nf < 2; ++nf) {
                short8 b = *(const short8*)(Wo1T + (size_t)(wv * 32 + nf * 16 + lr) * 256 + qi * 8 + kk);
                acc[nf] = __builtin_amdgcn_mfma_f32_16x16x32_bf16(a, b, acc[nf], 0, 0, 0);
            }
        }
        float v[2][4], s1[4] = {0.f,0.f,0.f,0.f}, s2[4] = {0.f,0.f,0.f,0.f};
        #pragma unroll
        for (int nf = 0; nf < 2; ++nf) {
            int c = wv * 32 + nf * 16 + lr;
            float bc = attn_b[768 + c];
            #pragma unroll
            for (int jj = 0; jj < 4; ++jj) {
                int row = n0 + qi * 4 + jj;
                float vv = acc[nf][jj] + bc + x[(size_t)row * D + c];
                v[nf][jj] = vv; s1[jj] += vv; s2[jj] += vv * vv;
            }
        }
        #pragma unroll
        for (int jj = 0; jj < 4; ++jj) {
            #pragma unroll
            for (int off = 1; off < 16; off <<= 1) {
                s1[jj] += __shfl_xor(s1[jj], off);
                s2[jj] += __shfl_xor(s2[jj], off);
            }
        }
        if (lr == 0) {
            #pragma unroll
            for (int jj = 0; jj < 4; ++jj) { redA[qi*4+jj][wv] = s1[jj]; redB[qi*4+jj][wv] = s2[jj]; }
        }
        __syncthreads();
        if (tid < 16) {
            float a1 = 0.f, a2 = 0.f;
            #pragma unroll
            for (int q8 = 0; q8 < 8; ++q8) { a1 += redA[tid][q8]; a2 += redB[tid][q8]; }
            float mu = a1 * (1.0f / D);
            float var = a2 * (1.0f / D) - mu * mu;
            stats[tid][0] = mu; stats[tid][1] = rsqrtf(var + EPS);
        }
        __syncthreads();
        #pragma unroll
        for (int nf = 0; nf < 2; ++nf) {
            int c = wv * 32 + nf * 16 + lr;
            float gg = ln_g[c], bb = ln_b[c];
            #pragma unroll
            for (int jj = 0; jj < 4; ++jj) {
                int ridx = qi * 4 + jj;
                float ov = (v[nf][jj] - stats[ridx][0]) * stats[ridx][1] * gg + bb;
                S[(size_t)(n0 + ridx) * D + c] = ov;
                Sb[ridx][c] = f2b(ov);
            }
        }
    }
    __syncthreads();

    // ---- Wq2 -> T2 (bf16 global) ----
    {
        const unsigned short* Wq2T = wB + 4 * 65536;
        f32x4 acc[2] = {};
        #pragma unroll
        for (int kk = 0; kk < 256; kk += 32) {
            short8 a = *(const short8*)&Sb[lr][qi * 8 + kk];
            #pragma unroll
            for (int nf = 0; nf < 2; ++nf) {
                short8 b = *(const short8*)(Wq2T + (size_t)(wv * 32 + nf * 16 + lr) * 256 + qi * 8 + kk);
                acc[nf] = __builtin_amdgcn_mfma_f32_16x16x32_bf16(a, b, acc[nf], 0, 0, 0);
            }
        }
        #pragma unroll
        for (int nf = 0; nf < 2; ++nf) {
            int c = wv * 32 + nf * 16 + lr;
            float bc = pattn_b[c];
            #pragma unroll
            for (int jj = 0; jj < 4; ++jj)
                T2b[(size_t)(n0 + qi * 4 + jj) * 256 + c] = f2b(acc[nf][jj] + bc);
        }
    }
}

// ---------------- tail: attn2(union) + Wo2+LN2 + FF1 + FF2+LN1+mask ----------------
__global__ __launch_bounds__(512)
void tail_kernel(const int* __restrict__ active,
                 const unsigned short* __restrict__ wB,
                 const float* __restrict__ pattn_b, const float* __restrict__ ff_b1,
                 const float* __restrict__ ff_b2,
                 const float* __restrict__ ln_g, const float* __restrict__ ln_b,
                 const unsigned short* __restrict__ k2b,
                 const unsigned short* __restrict__ v2b,
                 const float* __restrict__ S, const unsigned short* __restrict__ T2b,
                 float* __restrict__ out) {
    const int tid = threadIdx.x;
    const int wv = tid >> 6, lane = tid & 63;
    const int lr = lane & 15, qi = lane >> 4;
    const int n0 = blockIdx.x * 16;
    const int h = n0 >> 6, w0 = n0 & 63;

    __shared__ __align__(16) char smem[SMEM_SZ];
    unsigned short (*kvU)[256] = (unsigned short(*)[256])(smem + KV_OFF);
    float (*wgt)[8][25]        = (float(*)[8][25])(smem + WGT_OFF);
    float (*redA)[8]           = (float(*)[8])(smem + REDA_OFF);
    float (*redB)[8]           = (float(*)[8])(smem + REDB_OFF);
    float (*stats)[2]          = (float(*)[2])(smem + STAT_OFF);
    unsigned short (*T3b)[264] = (unsigned short(*)[264])(smem + T1B_OFF);
    float (*S2f)[260]          = (float(*)[260])(smem + S2F_OFF);
    unsigned short (*S2b)[264] = (unsigned short(*)[264])(smem + S2B_OFF);
    unsigned short (*Hb)[520]  = (unsigned short(*)[520])(smem + HB_OFF);

    load_union(k2b, h, w0, NN, kvU, tid);   // OOB -> bias row
    __syncthreads();

    const int half = lane >> 5, lam = lane & 31;
    const int m = wv * 2 + half;
    float q[8];
    {
        short8 qv = *(const short8*)(T2b + (size_t)(n0 + m) * 256 + lam * 8);
        #pragma unroll
        for (int j = 0; j < 8; ++j) q[j] = b2f(qv[j]);
    }
    #pragma unroll 5
    for (int l = 0; l < L; ++l) {
        int u = (l / 5) * 20 + m + (l % 5);
        short8 kv = *(const short8*)&kvU[u][lam * 8];
        float p = q[0] * b2f(kv[0]);
        #pragma unroll
        for (int j = 1; j < 8; ++j) p = fmaf(q[j], b2f(kv[j]), p);
        p += __shfl_xor(p, 1); p += __shfl_xor(p, 2);
        if ((lam & 3) == 0) wgt[m][lam >> 2][l] = p * SCALE;
    }
    __syncthreads();
    if (tid < 128) {
        int mm = tid >> 3, hd = tid & 7;
        float mx = -1e30f;
        for (int l = 0; l < L; ++l) mx = fmaxf(mx, wgt[mm][hd][l]);
        float sum = 0.0f;
        for (int l = 0; l < L; ++l) { float e = expf(wgt[mm][hd][l] - mx); wgt[mm][hd][l] = e; sum += e; }
        float inv = 1.0f / sum;
        for (int l = 0; l < L; ++l) wgt[mm][hd][l] *= inv;
    }
    __syncthreads();
    load_union(v2b, h, w0, NN, kvU, tid);
    __syncthreads();
    float o[8] = {0.f,0.f,0.f,0.f,0.f,0.f,0.f,0.f};
    #pragma unroll 5
    for (int l = 0; l < L; ++l) {
        int u = (l / 5) * 20 + m + (l % 5);
        float wt = wgt[m][lam >> 2][l];
        short8 v8 = *(const short8*)&kvU[u][lam * 8];
        #pragma unroll
        for (int j = 0; j < 8; ++j) o[j] = fmaf(wt, b2f(v8[j]), o[j]);
    }
    __syncthreads();
    {
        unsigned short u8[8];
        #pragma unroll
        for (int j = 0; j < 8; ++j) u8[j] = f2b(o[j]);
        *(uint4*)&T3b[m][lam * 8] = *(uint4*)u8;
    }
    __syncthreads();

    // ---- Wo2 + bias + resid(S) + LN2 -> S2f/S2b ----
    {
        const unsigned short* Wo2T = wB + 7 * 65536;
        f32x4 acc[2] = {};
        #pragma unroll
        for (int kk = 0; kk < 256; kk += 32) {
            short8 a = *(const short8*)&T3b[lr][qi * 8 + kk];
            #pragma unroll
            for (int nf = 0; nf < 2; ++nf) {
                short8 b = *(const short8*)(Wo2T + (size_t)(wv * 32 + nf * 16 + lr) * 256 + qi * 8 + kk);
                acc[nf] = __builtin_amdgcn_mfma_f32_16x16x32_bf16(a, b, acc[nf], 0, 0, 0);
            }
        }
        float v[2][4], s1[4] = {0.f,0.f,0.f,0.f}, s2[4] = {0.f,0.f,0.f,0.f};
        #pragma unroll
        for (int nf = 0; nf < 2; ++nf) {
            int c = wv * 32 + nf * 16 + lr;
            float bc = pattn_b[768 + c];
            #pragma unroll
            for (int jj = 0; jj < 4; ++jj) {
                int row = n0 + qi * 4 + jj;
                float vv = acc[nf][jj] + bc + S[(size_t)row * D + c];
                v[nf][jj] = vv; s1[jj] += vv; s2[jj] += vv * vv;
            }
        }
        #pragma unroll
        for (int jj = 0; jj < 4; ++jj) {
            #pragma unroll
            for (int off = 1; off < 16; off <<= 1) {
                s1[jj] += __shfl_xor(s1[jj], off);
                s2[jj] += __shfl_xor(s2[jj], off);
            }
        }
        if (lr == 0) {
            #pragma unroll
            for (int jj = 0; jj < 4; ++jj) { redA[qi*4+jj][wv] = s1[jj]; redB[qi*4+jj][wv] = s2[jj]; }
        }
        __syncthreads();
        if (tid < 16) {
            float a1 = 0.f, a2 = 0.f;
            #pragma unroll
            for (int q8 = 0; q8 < 8; ++q8) { a1 += redA[tid][q8]; a2 += redB[tid][q8]; }
            float mu = a1 * (1.0f / D);
            float var = a2 * (1.0f / D) - mu * mu;
            stats[tid][0] = mu; stats[tid][1] = rsqrtf(var + EPS);
        }
        __syncthreads();
        #pragma unroll
        for (int nf = 0; nf < 2; ++nf) {
            int c = wv * 32 + nf * 16 + lr;
            float gg = ln_g[512 + c], bb = ln_b[512 + c];
            #pragma unroll
            for (int jj = 0; jj < 4; ++jj) {
                int ridx = qi * 4 + jj;
                float ov = (v[nf][jj] - stats[ridx][0]) * stats[ridx][1] * gg + bb;
                S2f[ridx][c] = ov;
                S2b[ridx][c] = f2b(ov);
            }
        }
    }
    __syncthreads();

    // ---- FF1 -> Hb ----
    {
        const unsigned short* W1T = wB + 524288;
        f32x4 acc[4] = {};
        #pragma unroll
        for (int kk = 0; kk < 256; kk += 32) {
            short8 a = *(const short8*)&S2b[lr][qi * 8 + kk];
            #pragma unroll
            for (int nf = 0; nf < 4; ++nf) {
                short8 b = *(const short8*)(W1T + (size_t)(wv * 64 + nf * 16 + lr) * 256 + qi * 8 + kk);
                acc[nf] = __builtin_amdgcn_mfma_f32_16x16x32_bf16(a, b, acc[nf], 0, 0, 0);
            }
        }
        #pragma unroll
        for (int nf = 0; nf < 4; ++nf) {
            int c = wv * 64 + nf * 16 + lr;
            float bc = ff_b1[c];
            #pragma unroll
            for (int jj = 0; jj < 4; ++jj)
                Hb[qi * 4 + jj][c] = f2b(fmaxf(acc[nf][jj] + bc, 0.0f));
        }
    }
    __syncthreads();

    // ---- FF2 (K=512) + resid(S2f) + LN1 + mask -> out ----
    {
        const unsigned short* W2T = wB + 655360;
        f32x4 acc[2] = {};
        #pragma unroll
        for (int kk = 0; kk < 512; kk += 32) {
            short8 a = *(const short8*)&Hb[lr][qi * 8 + kk];
            #pragma unroll
            for (int nf = 0; nf < 2; ++nf) {
                short8 b = *(const short8*)(W2T + (size_t)(wv * 32 + nf * 16 + lr) * 512 + qi * 8 + kk);
                acc[nf] = __builtin_amdgcn_mfma_f32_16x16x32_bf16(a, b, acc[nf], 0, 0, 0);
            }
        }
        float v[2][4], s1[4] = {0.f,0.f,0.f,0.f}, s2[4] = {0.f,0.f,0.f,0.f};
        #pragma unroll
        for (int nf = 0; nf < 2; ++nf) {
            int c = wv * 32 + nf * 16 + lr;
            float bc = ff_b2[c];
            #pragma unroll
            for (int jj = 0; jj < 4; ++jj) {
                int ridx = qi * 4 + jj;
                float vv = acc[nf][jj] + bc + S2f[ridx][c];
                v[nf][jj] = vv; s1[jj] += vv; s2[jj] += vv * vv;
            }
        }
        #pragma unroll
        for (int jj = 0; jj < 4; ++jj) {
            #pragma unroll
            for (int off = 1; off < 16; off <<= 1) {
                s1[jj] += __shfl_xor(s1[jj], off);
                s2[jj] += __shfl_xor(s2[jj], off);
            }
        }
        if (lr == 0) {
            #pragma unroll
            for (int jj = 0; jj < 4; ++jj) { redA[qi*4+jj][wv] = s1[jj]; redB[qi*4+jj][wv] = s2[jj]; }
        }
        __syncthreads();
        if (tid < 16) {
            float a1 = 0.f, a2 = 0.f;
            #pragma unroll
            for (int q8 = 0; q8 < 8; ++q8) { a1 += redA[tid][q8]; a2 += redB[tid][q8]; }
            float mu = a1 * (1.0f / D);
            float var = a2 * (1.0f / D) - mu * mu;
            stats[tid][0] = mu; stats[tid][1] = rsqrtf(var + EPS);
        }
        __syncthreads();
        bool arow_act[4];
        #pragma unroll
        for (int jj = 0; jj < 4; ++jj) {
            int row = n0 + qi * 4 + jj;
            arow_act[jj] = act_at(active, row >> 6, row & 63);
        }
        #pragma unroll
        for (int nf = 0; nf < 2; ++nf) {
            int c = wv * 32 + nf * 16 + lr;
            float gg = ln_g[256 + c], bb = ln_b[256 + c];
            #pragma unroll
            for (int jj = 0; jj < 4; ++jj) {
                int ridx = qi * 4 + jj;
                float ov = (v[nf][jj] - stats[ridx][0]) * stats[ridx][1] * gg + bb;
                out[(size_t)(n0 + ridx) * D + c] = arow_act[jj] ? ov : 0.0f;
            }
        }
        if (tid < 16) {
            int row = n0 + tid;
            out[(size_t)NND + row] = act_at(active, row >> 6, row & 63) ? 1.0f : 0.0f;
        }
    }
}

extern "C" void kernel_launch(void* const* d_in, const int* in_sizes, int n_in,
                              void* d_out, int out_size, void* d_ws, size_t ws_size,
                              hipStream_t stream) {
    const float* x       = (const float*)d_in[0];
    const float* memory  = (const float*)d_in[1];
    const int*   active  = (const int*)d_in[2];
    const float* attn_w  = (const float*)d_in[3];
    const float* attn_b  = (const float*)d_in[4];
    const float* pattn_w = (const float*)d_in[5];
    const float* pattn_b = (const float*)d_in[6];
    const float* ff_w1   = (const float*)d_in[7];
    const float* ff_b1   = (const float*)d_in[8];
    const float* ff_w2   = (const float*)d_in[9];
    const float* ff_b2   = (const float*)d_in[10];
    const float* ln_g    = (const float*)d_in[11];
    const float* ln_b    = (const float*)d_in[12];
    float* out = (float*)d_out;

    unsigned short* wsb = (unsigned short*)d_ws;
    unsigned short* xmB  = wsb;
    unsigned short* memB = wsb + (size_t)NND;
    unsigned short* wB   = wsb + 2 * (size_t)NND;               // 786432 shorts
    unsigned short* q1b  = wB + 786432;
    unsigned short* k1b  = q1b + (size_t)NND;
    unsigned short* v1b  = k1b + (size_t)NND;
    unsigned short* k2b  = v1b + (size_t)NND;                   // 4097 rows
    unsigned short* v2b  = k2b + (size_t)NND + 256;             // 4097 rows
    unsigned short* T2b  = v2b + (size_t)NND + 256;
    float* S = (float*)(T2b + (size_t)NND);                     // f32, 4 MB

    hipLaunchKernelGGL(prep_kernel, dim3(704), dim3(256), 0, stream,
                       x, memory, active, attn_w, pattn_w, ff_w1, ff_w2, pattn_b,
                       xmB, memB, wB, k2b + (size_t)NND, v2b + (size_t)NND);
    hipLaunchKernelGGL(proj_gemm, dim3(64, 20), dim3(256), 0, stream,
                       xmB, memB, wB, attn_b, pattn_b, q1b, k1b, v1b, k2b, v2b);
    hipLaunchKernelGGL(head_kernel, dim3(256), dim3(512), 0, stream,
                       active, x, wB, attn_b, pattn_b, ln_g, ln_b,
                       q1b, k1b, v1b, S, T2b);
    hipLaunchKernelGGL(tail_kernel, dim3(256), dim3(512), 0, stream,
                       active, wB, pattn_b, ff_b1, ff_b2, ln_g, ln_b,
                       k2b, v2b, S, T2b, out);
}

// Round 9
// 91.109 us; speedup vs baseline: 3.9064x; 1.0234x over previous
//
#include <hip/hip_runtime.h>
#include <math.h>

#define D 256
#define H2 512
#define HEADS 8
#define L 25
#define GH 64
#define GW 64
#define NN 4096
#define EPS 1e-5f
#define SCALE 0.17677669529663687f  // 1/sqrt(32)
#define NND 1048576                 // NN*D

typedef __attribute__((ext_vector_type(8))) short short8;
typedef __attribute__((ext_vector_type(4))) float f32x4;

__device__ __forceinline__ bool act_at(const int* __restrict__ active, int h, int w) {
    if (h < 0 || h >= GH || w < 0 || w >= GW) return false;
    if (h == 2 && w == 2) return false;   // ap.at[:, center, center].set(False) quirk
    return active[h * GW + w] != 0;
}

__device__ __forceinline__ unsigned short f2b(float f) {
    unsigned u = __float_as_uint(f);
    u += 0x7fffu + ((u >> 16) & 1u);      // RNE
    return (unsigned short)(u >> 16);
}
__device__ __forceinline__ float b2f(short v) {
    return __uint_as_float(((unsigned)(unsigned short)v) << 16);
}

// ---------------- prep: bf16 conversions + LDS-tiled weight transposes ----------------
__global__ __launch_bounds__(256)
void prep_kernel(const float* __restrict__ x, const float* __restrict__ mem,
                 const int* __restrict__ active,
                 const float* __restrict__ attn_w, const float* __restrict__ pattn_w,
                 const float* __restrict__ ff_w1, const float* __restrict__ ff_w2,
                 const float* __restrict__ pattn_b,
                 unsigned short* __restrict__ xmB, unsigned short* __restrict__ memB,
                 unsigned short* __restrict__ wB,
                 unsigned short* __restrict__ k2bias, unsigned short* __restrict__ v2bias) {
    const int tid = threadIdx.x;
    const int bid = blockIdx.x;
    if (bid < 192) {
        __shared__ float tile[64][65];
        const float* src; unsigned short* dst;
        int i0, n0, srcLen, dstLen;
        if (bid < 128) {
            int mat = bid >> 4, t16 = bid & 15;
            i0 = (t16 >> 2) * 64; n0 = (t16 & 3) * 64;
            src = (mat < 4) ? (attn_w + mat * 65536) : (pattn_w + (mat - 4) * 65536);
            dst = wB + mat * 65536;
            srcLen = 256; dstLen = 256;
        } else if (bid < 160) {
            int t = bid - 128;
            i0 = (t >> 3) * 64; n0 = (t & 7) * 64;
            src = ff_w1; dst = wB + 524288;      // W1T: [512][256]
            srcLen = 512; dstLen = 256;
        } else {
            int t = bid - 160;
            i0 = (t >> 2) * 64; n0 = (t & 3) * 64;
            src = ff_w2; dst = wB + 655360;      // W2T: [256][512]
            srcLen = 256; dstLen = 512;
        }
        int c = tid & 63, r4 = tid >> 6;
        for (int rr = 0; rr < 64; rr += 4)
            tile[rr + r4][c] = src[(size_t)(i0 + rr + r4) * srcLen + n0 + c];
        __syncthreads();
        for (int rr = 0; rr < 64; rr += 4) {
            int r = rr + r4;
            dst[(size_t)(n0 + r) * dstLen + i0 + c] = f2b(tile[c][r]);
        }
    } else {
        const int t0 = (bid - 192) * 256 + tid;
        for (int t = t0; t < 524800; t += 512 * 256) {
            if (t < 262144) {
                int n = t >> 6;
                bool a = act_at(active, n >> 6, n & 63);
                float4 v = ((const float4*)x)[t];
                ushort4 u;
                u.x = f2b(a ? v.x : 0.0f); u.y = f2b(a ? v.y : 0.0f);
                u.z = f2b(a ? v.z : 0.0f); u.w = f2b(a ? v.w : 0.0f);
                ((ushort4*)xmB)[t] = u;
            } else if (t < 524288) {
                int tt = t - 262144;
                float4 v = ((const float4*)mem)[tt];
                ushort4 u;
                u.x = f2b(v.x); u.y = f2b(v.y); u.z = f2b(v.z); u.w = f2b(v.w);
                ((ushort4*)memB)[tt] = u;
            } else {
                int tt = t - 524288;   // 512 scalars: K2/V2 bias rows (row 4096, bf16)
                if (tt < 256) k2bias[tt] = f2b(pattn_b[256 + tt]);
                else          v2bias[tt - 256] = f2b(pattn_b[512 + (tt - 256)]);
            }
        }
    }
}

// ---------------- proj: 5 GEMM streams -> bf16 outputs ----------------
__global__ __launch_bounds__(256)
void proj_gemm(const unsigned short* __restrict__ xmB,
               const unsigned short* __restrict__ memB,
               const unsigned short* __restrict__ wB,
               const float* __restrict__ attn_b, const float* __restrict__ pattn_b,
               unsigned short* __restrict__ q1b, unsigned short* __restrict__ k1b,
               unsigned short* __restrict__ v1b, unsigned short* __restrict__ k2b,
               unsigned short* __restrict__ v2b) {
    const int s  = blockIdx.y >> 2;       // 0:Q1 1:K1 2:V1 3:K2 4:V2
    const int n0 = (blockIdx.y & 3) * 64;
    const unsigned short* A  = (s < 3) ? xmB : memB;
    const int wtIdx = (s < 3) ? s : (s + 2);            // K2->5, V2->6
    const unsigned short* WT = wB + (size_t)wtIdx * 65536;
    const float* bias = (s < 3) ? (attn_b + s * 256) : (pattn_b + (s - 2) * 256);
    unsigned short* outB;
    switch (s) { case 0: outB = q1b; break; case 1: outB = k1b; break;
                 case 2: outB = v1b; break; case 3: outB = k2b; break;
                 default: outB = v2b; }

    const int tid = threadIdx.x;
    const int wave = tid >> 6, lane = tid & 63;
    const int m0 = blockIdx.x * 64 + wave * 16;
    const int lr = lane & 15;
    const int lk = (lane >> 4) << 3;
    f32x4 acc[4] = {};
    const unsigned short* arow = A  + (size_t)(m0 + lr) * 256 + lk;
    const unsigned short* brow = WT + (size_t)(n0 + lr) * 256 + lk;
    #pragma unroll
    for (int kk = 0; kk < 256; kk += 32) {
        short8 a = *(const short8*)(arow + kk);
        #pragma unroll
        for (int nf = 0; nf < 4; ++nf) {
            short8 b = *(const short8*)(brow + (size_t)nf * 16 * 256 + kk);
            acc[nf] = __builtin_amdgcn_mfma_f32_16x16x32_bf16(a, b, acc[nf], 0, 0, 0);
        }
    }
    const int rbase = m0 + ((lane >> 4) << 2);
    #pragma unroll
    for (int nf = 0; nf < 4; ++nf) {
        int c = n0 + nf * 16 + lr;
        float bc = bias[c];
        #pragma unroll
        for (int jj = 0; jj < 4; ++jj)
            outB[(size_t)(rbase + jj) * 256 + c] = f2b(acc[nf][jj] + bc);
    }
}

// ---------------- LDS layout ----------------
#define KV_OFF   0            // union: 100 rows x 256 bf16 = 51200
#define ACT_OFF  51200        // 128
#define WGT_OFF  51328        // [16][8][25] f32 = 12800
#define REDA_OFF 64128        // 512
#define REDB_OFF 64640        // 512
#define STAT_OFF 65152        // 128
#define SMEM_SZ  65280
// aliases into [0,51200):
#define T1B_OFF  0            // [16][264] bf16 = 8448  (also T2b staging, T3b)
#define SB_OFF   8448         // [16][264] bf16 = 8448  (also S2b)
#define HB_OFF   16896        // [16][520] bf16 = 16640

__device__ __forceinline__ void load_union(const unsigned short* __restrict__ base,
                                           int h, int w0, int fallback,
                                           unsigned short (*kvU)[256], int tid) {
    for (int c = tid; c < 3200; c += 512) {
        int u = c >> 5, part = c & 31;
        int r = u / 20;
        int hh = h - 2 + r, ww = w0 - 2 + (u - r * 20);
        bool ib = ((unsigned)hh < GH) && ((unsigned)ww < GW);
        int row = ib ? ((hh << 6) | ww) : fallback;
        *(uint4*)&kvU[u][part * 8] = *(const uint4*)(base + (size_t)row * 256 + part * 8);
    }
}

// ---------------- fused: attn1 + Wo1+LN0 + Wq2 + attn2 + Wo2+LN2 + FF1 + FF2+LN1 ----
__global__ __launch_bounds__(512)
void fused_kernel(const int* __restrict__ active, const float* __restrict__ x,
                  const unsigned short* __restrict__ wB,
                  const float* __restrict__ attn_b, const float* __restrict__ pattn_b,
                  const float* __restrict__ ff_b1, const float* __restrict__ ff_b2,
                  const float* __restrict__ ln_g, const float* __restrict__ ln_b,
                  const unsigned short* __restrict__ q1b,
                  const unsigned short* __restrict__ k1b,
                  const unsigned short* __restrict__ v1b,
                  const unsigned short* __restrict__ k2b,
                  const unsigned short* __restrict__ v2b,
                  float* __restrict__ out) {
    const int tid = threadIdx.x;
    const int wv = tid >> 6, lane = tid & 63;
    const int lr = lane & 15, qi = lane >> 4;
    const int bid = ((blockIdx.x & 7) << 5) | (blockIdx.x >> 3);   // XCD-chunked swizzle
    const int n0 = bid * 16;
    const int h = n0 >> 6, w0 = n0 & 63;
    const int half = lane >> 5, lam = lane & 31;
    const int m = wv * 2 + half;

    __shared__ __align__(16) char smem[SMEM_SZ];
    unsigned short (*kvU)[256] = (unsigned short(*)[256])(smem + KV_OFF);
    unsigned char* actU        = (unsigned char*)(smem + ACT_OFF);
    float (*wgt)[8][25]        = (float(*)[8][25])(smem + WGT_OFF);
    float (*redA)[8]           = (float(*)[8])(smem + REDA_OFF);
    float (*redB)[8]           = (float(*)[8])(smem + REDB_OFF);
    float (*stats)[2]          = (float(*)[2])(smem + STAT_OFF);
    unsigned short (*T1b)[264] = (unsigned short(*)[264])(smem + T1B_OFF);
    unsigned short (*Sb)[264]  = (unsigned short(*)[264])(smem + SB_OFF);
    unsigned short (*Hb)[520]  = (unsigned short(*)[520])(smem + HB_OFF);

    // ---- phase 1: masks + K1 union ----
    if (tid < 100) {
        int r = tid / 20;
        int hh = h - 2 + r, ww = w0 - 2 + (tid - r * 20);
        actU[tid] = act_at(active, hh, ww) ? 1 : 0;
    }
    load_union(k1b, h, w0, 0, kvU, tid);
    __syncthreads();

    // ---- attn1 scores ----
    {
        float q[8];
        short8 qv = *(const short8*)(q1b + (size_t)(n0 + m) * 256 + lam * 8);
        #pragma unroll
        for (int j = 0; j < 8; ++j) q[j] = b2f(qv[j]);
        #pragma unroll 5
        for (int l = 0; l < L; ++l) {
            int u = (l / 5) * 20 + m + (l % 5);
            short8 kv = *(const short8*)&kvU[u][lam * 8];
            float p = q[0] * b2f(kv[0]);
            #pragma unroll
            for (int j = 1; j < 8; ++j) p = fmaf(q[j], b2f(kv[j]), p);
            p += __shfl_xor(p, 1); p += __shfl_xor(p, 2);
            float sv = actU[u] ? p * SCALE : -1e30f;
            if ((lam & 3) == 0) wgt[m][lam >> 2][l] = sv;
        }
    }
    __syncthreads();
    if (tid < 128) {
        int mm = tid >> 3, hd = tid & 7;
        float mx = -1e30f;
        for (int l = 0; l < L; ++l) mx = fmaxf(mx, wgt[mm][hd][l]);
        float sum = 0.0f;
        for (int l = 0; l < L; ++l) { float e = expf(wgt[mm][hd][l] - mx); wgt[mm][hd][l] = e; sum += e; }
        float inv = 1.0f / sum;
        for (int l = 0; l < L; ++l) wgt[mm][hd][l] *= inv;
    }
    __syncthreads();
    load_union(v1b, h, w0, 0, kvU, tid);
    __syncthreads();
    // ---- PV1 -> T1b ----
    {
        float o[8] = {0.f,0.f,0.f,0.f,0.f,0.f,0.f,0.f};
        #pragma unroll 5
        for (int l = 0; l < L; ++l) {
            int u = (l / 5) * 20 + m + (l % 5);
            if (actU[u]) {
                float wt = wgt[m][lam >> 2][l];
                short8 v8 = *(const short8*)&kvU[u][lam * 8];
                #pragma unroll
                for (int j = 0; j < 8; ++j) o[j] = fmaf(wt, b2f(v8[j]), o[j]);
            }
        }
        __syncthreads();
        unsigned short u8[8];
        #pragma unroll
        for (int j = 0; j < 8; ++j) u8[j] = f2b(o[j]);
        *(uint4*)&T1b[m][lam * 8] = *(uint4*)u8;
    }
    __syncthreads();

    // ---- Wo1 + bias + resid(x) + LN0 -> sreg + Sb ----
    float sreg[2][4];
    {
        const unsigned short* Wo1T = wB + 3 * 65536;
        f32x4 acc[2] = {};
        #pragma unroll
        for (int kk = 0; kk < 256; kk += 32) {
            short8 a = *(const short8*)&T1b[lr][qi * 8 + kk];
            #pragma unroll
            for (int nf = 0; nf < 2; ++nf) {
                short8 b = *(const short8*)(Wo1T + (size_t)(wv * 32 + nf * 16 + lr) * 256 + qi * 8 + kk);
                acc[nf] = __builtin_amdgcn_mfma_f32_16x16x32_bf16(a, b, acc[nf], 0, 0, 0);
            }
        }
        float v[2][4], s1[4] = {0.f,0.f,0.f,0.f}, s2[4] = {0.f,0.f,0.f,0.f};
        #pragma unroll
        for (int nf = 0; nf < 2; ++nf) {
            int c = wv * 32 + nf * 16 + lr;
            float bc = attn_b[768 + c];
            #pragma unroll
            for (int jj = 0; jj < 4; ++jj) {
                int row = n0 + qi * 4 + jj;
                float vv = acc[nf][jj] + bc + x[(size_t)row * D + c];
                v[nf][jj] = vv; s1[jj] += vv; s2[jj] += vv * vv;
            }
        }
        #pragma unroll
        for (int jj = 0; jj < 4; ++jj) {
            #pragma unroll
            for (int off = 1; off < 16; off <<= 1) {
                s1[jj] += __shfl_xor(s1[jj], off);
                s2[jj] += __shfl_xor(s2[jj], off);
            }
        }
        if (lr == 0) {
            #pragma unroll
            for (int jj = 0; jj < 4; ++jj) { redA[qi*4+jj][wv] = s1[jj]; redB[qi*4+jj][wv] = s2[jj]; }
        }
        __syncthreads();
        if (tid < 16) {
            float a1 = 0.f, a2 = 0.f;
            #pragma unroll
            for (int q8 = 0; q8 < 8; ++q8) { a1 += redA[tid][q8]; a2 += redB[tid][q8]; }
            float mu = a1 * (1.0f / D);
            float var = a2 * (1.0f / D) - mu * mu;
            stats[tid][0] = mu; stats[tid][1] = rsqrtf(var + EPS);
        }
        __syncthreads();
        #pragma unroll
        for (int nf = 0; nf < 2; ++nf) {
            int c = wv * 32 + nf * 16 + lr;
            float gg = ln_g[c], bb = ln_b[c];
            #pragma unroll
            for (int jj = 0; jj < 4; ++jj) {
                int ridx = qi * 4 + jj;
                float ov = (v[nf][jj] - stats[ridx][0]) * stats[ridx][1] * gg + bb;
                sreg[nf][jj] = ov;
                Sb[ridx][c] = f2b(ov);
            }
        }
    }
    __syncthreads();

    // ---- Wq2 -> T2 staged via LDS (T1b region) ----
    {
        const unsigned short* Wq2T = wB + 4 * 65536;
        f32x4 acc[2] = {};
        #pragma unroll
        for (int kk = 0; kk < 256; kk += 32) {
            short8 a = *(const short8*)&Sb[lr][qi * 8 + kk];
            #pragma unroll
            for (int nf = 0; nf < 2; ++nf) {
                short8 b = *(const short8*)(Wq2T + (size_t)(wv * 32 + nf * 16 + lr) * 256 + qi * 8 + kk);
                acc[nf] = __builtin_amdgcn_mfma_f32_16x16x32_bf16(a, b, acc[nf], 0, 0, 0);
            }
        }
        __syncthreads();
        #pragma unroll
        for (int nf = 0; nf < 2; ++nf) {
            int c = wv * 32 + nf * 16 + lr;
            float bc = pattn_b[c];
            #pragma unroll
            for (int jj = 0; jj < 4; ++jj)
                T1b[qi * 4 + jj][c] = f2b(acc[nf][jj] + bc);
        }
    }
    __syncthreads();

    // ---- read q2 into regs, then overwrite LDS with K2 union ----
    float q2[8];
    {
        short8 qv = *(const short8*)&T1b[m][lam * 8];
        #pragma unroll
        for (int j = 0; j < 8; ++j) q2[j] = b2f(qv[j]);
    }
    __syncthreads();
    load_union(k2b, h, w0, NN, kvU, tid);   // OOB -> bias row
    __syncthreads();

    // ---- attn2 scores ----
    #pragma unroll 5
    for (int l = 0; l < L; ++l) {
        int u = (l / 5) * 20 + m + (l % 5);
        short8 kv = *(const short8*)&kvU[u][lam * 8];
        float p = q2[0] * b2f(kv[0]);
        #pragma unroll
        for (int j = 1; j < 8; ++j) p = fmaf(q2[j], b2f(kv[j]), p);
        p += __shfl_xor(p, 1); p += __shfl_xor(p, 2);
        if ((lam & 3) == 0) wgt[m][lam >> 2][l] = p * SCALE;
    }
    __syncthreads();
    if (tid < 128) {
        int mm = tid >> 3, hd = tid & 7;
        float mx = -1e30f;
        for (int l = 0; l < L; ++l) mx = fmaxf(mx, wgt[mm][hd][l]);
        float sum = 0.0f;
        for (int l = 0; l < L; ++l) { float e = expf(wgt[mm][hd][l] - mx); wgt[mm][hd][l] = e; sum += e; }
        float inv = 1.0f / sum;
        for (int l = 0; l < L; ++l) wgt[mm][hd][l] *= inv;
    }
    __syncthreads();
    load_union(v2b, h, w0, NN, kvU, tid);
    __syncthreads();
    // ---- PV2 -> T3b (T1b region) ----
    {
        float o[8] = {0.f,0.f,0.f,0.f,0.f,0.f,0.f,0.f};
        #pragma unroll 5
        for (int l = 0; l < L; ++l) {
            int u = (l / 5) * 20 + m + (l % 5);
            float wt = wgt[m][lam >> 2][l];
            short8 v8 = *(const short8*)&kvU[u][lam * 8];
            #pragma unroll
            for (int j = 0; j < 8; ++j) o[j] = fmaf(wt, b2f(v8[j]), o[j]);
        }
        __syncthreads();
        unsigned short u8[8];
        #pragma unroll
        for (int j = 0; j < 8; ++j) u8[j] = f2b(o[j]);
        *(uint4*)&T1b[m][lam * 8] = *(uint4*)u8;
    }
    __syncthreads();

    // ---- Wo2 + bias + resid(sreg) + LN2 -> s2reg + Sb(S2b) ----
    float s2reg[2][4];
    {
        const unsigned short* Wo2T = wB + 7 * 65536;
        f32x4 acc[2] = {};
        #pragma unroll
        for (int kk = 0; kk < 256; kk += 32) {
            short8 a = *(const short8*)&T1b[lr][qi * 8 + kk];
            #pragma unroll
            for (int nf = 0; nf < 2; ++nf) {
                short8 b = *(const short8*)(Wo2T + (size_t)(wv * 32 + nf * 16 + lr) * 256 + qi * 8 + kk);
                acc[nf] = __builtin_amdgcn_mfma_f32_16x16x32_bf16(a, b, acc[nf], 0, 0, 0);
            }
        }
        float v[2][4], s1[4] = {0.f,0.f,0.f,0.f}, s2[4] = {0.f,0.f,0.f,0.f};
        #pragma unroll
        for (int nf = 0; nf < 2; ++nf) {
            int c = wv * 32 + nf * 16 + lr;
            float bc = pattn_b[768 + c];
            #pragma unroll
            for (int jj = 0; jj < 4; ++jj) {
                float vv = acc[nf][jj] + bc + sreg[nf][jj];
                v[nf][jj] = vv; s1[jj] += vv; s2[jj] += vv * vv;
            }
        }
        #pragma unroll
        for (int jj = 0; jj < 4; ++jj) {
            #pragma unroll
            for (int off = 1; off < 16; off <<= 1) {
                s1[jj] += __shfl_xor(s1[jj], off);
                s2[jj] += __shfl_xor(s2[jj], off);
            }
        }
        if (lr == 0) {
            #pragma unroll
            for (int jj = 0; jj < 4; ++jj) { redA[qi*4+jj][wv] = s1[jj]; redB[qi*4+jj][wv] = s2[jj]; }
        }
        __syncthreads();
        if (tid < 16) {
            float a1 = 0.f, a2 = 0.f;
            #pragma unroll
            for (int q8 = 0; q8 < 8; ++q8) { a1 += redA[tid][q8]; a2 += redB[tid][q8]; }
            float mu = a1 * (1.0f / D);
            float var = a2 * (1.0f / D) - mu * mu;
            stats[tid][0] = mu; stats[tid][1] = rsqrtf(var + EPS);
        }
        __syncthreads();
        #pragma unroll
        for (int nf = 0; nf < 2; ++nf) {
            int c = wv * 32 + nf * 16 + lr;
            float gg = ln_g[512 + c], bb = ln_b[512 + c];
            #pragma unroll
            for (int jj = 0; jj < 4; ++jj) {
                int ridx = qi * 4 + jj;
                float ov = (v[nf][jj] - stats[ridx][0]) * stats[ridx][1] * gg + bb;
                s2reg[nf][jj] = ov;
                Sb[ridx][c] = f2b(ov);
            }
        }
    }
    __syncthreads();

    // ---- FF1 (A from Sb) -> Hb ----
    {
        const unsigned short* W1T = wB + 524288;
        f32x4 acc[4] = {};
        #pragma unroll
        for (int kk = 0; kk < 256; kk += 32) {
            short8 a = *(const short8*)&Sb[lr][qi * 8 + kk];
            #pragma unroll
            for (int nf = 0; nf < 4; ++nf) {
                short8 b = *(const short8*)(W1T + (size_t)(wv * 64 + nf * 16 + lr) * 256 + qi * 8 + kk);
                acc[nf] = __builtin_amdgcn_mfma_f32_16x16x32_bf16(a, b, acc[nf], 0, 0, 0);
            }
        }
        #pragma unroll
        for (int nf = 0; nf < 4; ++nf) {
            int c = wv * 64 + nf * 16 + lr;
            float bc = ff_b1[c];
            #pragma unroll
            for (int jj = 0; jj < 4; ++jj)
                Hb[qi * 4 + jj][c] = f2b(fmaxf(acc[nf][jj] + bc, 0.0f));
        }
    }
    __syncthreads();

    // ---- FF2 (K=512) + resid(s2reg) + LN1 + mask -> out ----
    {
        const unsigned short* W2T = wB + 655360;
        f32x4 acc[2] = {};
        #pragma unroll
        for (int kk = 0; kk < 512; kk += 32) {
            short8 a = *(const short8*)&Hb[lr][qi * 8 + kk];
            #pragma unroll
            for (int nf = 0; nf < 2; ++nf) {
                short8 b = *(const short8*)(W2T + (size_t)(wv * 32 + nf * 16 + lr) * 512 + qi * 8 + kk);
                acc[nf] = __builtin_amdgcn_mfma_f32_16x16x32_bf16(a, b, acc[nf], 0, 0, 0);
            }
        }
        float v[2][4], s1[4] = {0.f,0.f,0.f,0.f}, s2[4] = {0.f,0.f,0.f,0.f};
        #pragma unroll
        for (int nf = 0; nf < 2; ++nf) {
            int c = wv * 32 + nf * 16 + lr;
            float bc = ff_b2[c];
            #pragma unroll
            for (int jj = 0; jj < 4; ++jj) {
                float vv = acc[nf][jj] + bc + s2reg[nf][jj];
                v[nf][jj] = vv; s1[jj] += vv; s2[jj] += vv * vv;
            }
        }
        #pragma unroll
        for (int jj = 0; jj < 4; ++jj) {
            #pragma unroll
            for (int off = 1; off < 16; off <<= 1) {
                s1[jj] += __shfl_xor(s1[jj], off);
                s2[jj] += __shfl_xor(s2[jj], off);
            }
        }
        if (lr == 0) {
            #pragma unroll
            for (int jj = 0; jj < 4; ++jj) { redA[qi*4+jj][wv] = s1[jj]; redB[qi*4+jj][wv] = s2[jj]; }
        }
        __syncthreads();
        if (tid < 16) {
            float a1 = 0.f, a2 = 0.f;
            #pragma unroll
            for (int q8 = 0; q8 < 8; ++q8) { a1 += redA[tid][q8]; a2 += redB[tid][q8]; }
            float mu = a1 * (1.0f / D);
            float var = a2 * (1.0f / D) - mu * mu;
            stats[tid][0] = mu; stats[tid][1] = rsqrtf(var + EPS);
        }
        __syncthreads();
        bool arow_act[4];
        #pragma unroll
        for (int jj = 0; jj < 4; ++jj) {
            int row = n0 + qi * 4 + jj;
            arow_act[jj] = act_at(active, row >> 6, row & 63);
        }
        #pragma unroll
        for (int nf = 0; nf < 2; ++nf) {
            int c = wv * 32 + nf * 16 + lr;
            float gg = ln_g[256 + c], bb = ln_b[256 + c];
            #pragma unroll
            for (int jj = 0; jj < 4; ++jj) {
                int ridx = qi * 4 + jj;
                float ov = (v[nf][jj] - stats[ridx][0]) * stats[ridx][1] * gg + bb;
                out[(size_t)(n0 + ridx) * D + c] = arow_act[jj] ? ov : 0.0f;
            }
        }
        if (tid < 16) {
            int row = n0 + tid;
            out[(size_t)NND + row] = act_at(active, row >> 6, row & 63) ? 1.0f : 0.0f;
        }
    }
}

extern "C" void kernel_launch(void* const* d_in, const int* in_sizes, int n_in,
                              void* d_out, int out_size, void* d_ws, size_t ws_size,
                              hipStream_t stream) {
    const float* x       = (const float*)d_in[0];
    const float* memory  = (const float*)d_in[1];
    const int*   active  = (const int*)d_in[2];
    const float* attn_w  = (const float*)d_in[3];
    const float* attn_b  = (const float*)d_in[4];
    const float* pattn_w = (const float*)d_in[5];
    const float* pattn_b = (const float*)d_in[6];
    const float* ff_w1   = (const float*)d_in[7];
    const float* ff_b1   = (const float*)d_in[8];
    const float* ff_w2   = (const float*)d_in[9];
    const float* ff_b2   = (const float*)d_in[10];
    const float* ln_g    = (const float*)d_in[11];
    const float* ln_b    = (const float*)d_in[12];
    float* out = (float*)d_out;

    unsigned short* wsb = (unsigned short*)d_ws;
    unsigned short* xmB  = wsb;
    unsigned short* memB = wsb + (size_t)NND;
    unsigned short* wB   = wsb + 2 * (size_t)NND;               // 786432 shorts
    unsigned short* q1b  = wB + 786432;
    unsigned short* k1b  = q1b + (size_t)NND;
    unsigned short* v1b  = k1b + (size_t)NND;
    unsigned short* k2b  = v1b + (size_t)NND;                   // 4097 rows
    unsigned short* v2b  = k2b + (size_t)NND + 256;             // 4097 rows

    hipLaunchKernelGGL(prep_kernel, dim3(704), dim3(256), 0, stream,
                       x, memory, active, attn_w, pattn_w, ff_w1, ff_w2, pattn_b,
                       xmB, memB, wB, k2b + (size_t)NND, v2b + (size_t)NND);
    hipLaunchKernelGGL(proj_gemm, dim3(64, 20), dim3(256), 0, stream,
                       xmB, memB, wB, attn_b, pattn_b, q1b, k1b, v1b, k2b, v2b);
    hipLaunchKernelGGL(fused_kernel, dim3(256), dim3(512), 0, stream,
                       active, x, wB, attn_b, pattn_b, ff_b1, ff_b2, ln_g, ln_b,
                       q1b, k1b, v1b, k2b, v2b, out);
}